// Round 2
// baseline (822.060 us; speedup 1.0000x reference)
//
#include <hip/hip_runtime.h>
#include <cstdint>
#include <cstddef>

typedef unsigned short USHORT;
typedef __bf16 bf16x8 __attribute__((ext_vector_type(8)));
typedef float f32x4 __attribute__((ext_vector_type(4)));

__device__ __forceinline__ float b2f(USHORT u) {
    union { unsigned int i; float f; } v; v.i = ((unsigned int)u) << 16; return v.f;
}
__device__ __forceinline__ USHORT f2bf(float f) {
    union { float f; unsigned int i; } v; v.f = f;
    unsigned int u = v.i;
    unsigned int r = (u + 0x7FFFu + ((u >> 16) & 1u)) >> 16;
    return (USHORT)r;
}

__device__ __forceinline__ void gload_lds16(const void* g, void* l) {
    __builtin_amdgcn_global_load_lds(
        (const __attribute__((address_space(1))) void*)(uintptr_t)g,
        (__attribute__((address_space(3))) void*)(uint32_t)(uintptr_t)l,
        16, 0, 0);
}

// ---------------- f32 -> bf16 conversion (weights), 4 elems/thread ----------
__global__ __launch_bounds__(256)
void f2b_kernel(const float* __restrict__ src, USHORT* __restrict__ dst, int n)
{
    int i = (blockIdx.x * 256 + threadIdx.x) * 4;
    if (i < n) {
        float4 v = *(const float4*)(src + i);
        ushort4 o;
        o.x = f2bf(v.x); o.y = f2bf(v.y); o.z = f2bf(v.z); o.w = f2bf(v.w);
        *(ushort4*)(dst + i) = o;
    }
}

// ---------------- LayerNorm: f32 in -> bf16 out. 1 block/token, 256 thr ----
__global__ __launch_bounds__(256)
void ln_kernel(const float* __restrict__ inp, const float* __restrict__ g,
               const float* __restrict__ bsh, USHORT* __restrict__ out)
{
    const int tid = threadIdx.x;
    const size_t row = blockIdx.x;
    float4 t = ((const float4*)inp)[row * 256 + tid];
    float v[4] = { t.x, t.y, t.z, t.w };
    float s = v[0] + v[1] + v[2] + v[3];
    float sq = v[0]*v[0] + v[1]*v[1] + v[2]*v[2] + v[3]*v[3];
    #pragma unroll
    for (int off = 32; off; off >>= 1) { s += __shfl_down(s, off); sq += __shfl_down(sq, off); }
    __shared__ float red[8];
    const int wv = tid >> 6;
    if ((tid & 63) == 0) { red[wv] = s; red[wv + 4] = sq; }
    __syncthreads();
    const float S  = red[0] + red[1] + red[2] + red[3];
    const float SQ = red[4] + red[5] + red[6] + red[7];
    const float mu = S * (1.0f / 1024.0f);
    const float var = SQ * (1.0f / 1024.0f) - mu * mu;
    const float rs = rsqrtf(var + 1e-5f);
    float4 gv = ((const float4*)g)[tid];
    float4 bv = ((const float4*)bsh)[tid];
    ushort4 o;
    o.x = f2bf((v[0] - mu) * rs * gv.x + bv.x);
    o.y = f2bf((v[1] - mu) * rs * gv.y + bv.y);
    o.z = f2bf((v[2] - mu) * rs * gv.z + bv.z);
    o.w = f2bf((v[3] - mu) * rs * gv.w + bv.w);
    ((ushort4*)out)[row * 256 + tid] = o;
}

// ---------------- GEMM: C(M,N) = A(M,K) @ B(N,K)^T, bf16 MFMA, fused epilogue
// EPI 0: softplus -> f32 out; EPI 1: exact gelu -> bf16 out; EPI 2: +extra -> f32 out
template<int EPI>
__global__ __launch_bounds__(256)
void gemm_bt(const USHORT* __restrict__ A, const USHORT* __restrict__ B,
             const float* __restrict__ bias, const float* __restrict__ extra,
             void* __restrict__ outp, int M, int N, int K)
{
    __shared__ __align__(16) USHORT As[128 * 32];
    __shared__ __align__(16) USHORT Bs[128 * 32];
    const int tid = threadIdx.x;
    const int lane = tid & 63;
    const int w = tid >> 6;
    const int wr = w >> 1, wc = w & 1;
    const int tm = blockIdx.y * 128;
    const int tn = blockIdx.x * 128;

    f32x4 acc[4][4];
    #pragma unroll
    for (int i = 0; i < 4; i++)
        #pragma unroll
        for (int j = 0; j < 4; j++) acc[i][j] = (f32x4){0.f, 0.f, 0.f, 0.f};

    const int srow = tid >> 2;          // 0..63
    const int scol = (tid & 3) * 8;     // 0,8,16,24
    const USHORT* gA0 = A + (size_t)(tm + srow) * K + scol;
    const USHORT* gA1 = A + (size_t)(tm + 64 + srow) * K + scol;
    const USHORT* gB0 = B + (size_t)(tn + srow) * K + scol;
    const USHORT* gB1 = B + (size_t)(tn + 64 + srow) * K + scol;
    USHORT* lA0 = As + w * 512;          // wave-uniform LDS bases
    USHORT* lA1 = As + 2048 + w * 512;
    USHORT* lB0 = Bs + w * 512;
    USHORT* lB1 = Bs + 2048 + w * 512;

    const int fr = lane & 15;
    const int fko = (lane >> 4) * 8;

    for (int k0 = 0; k0 < K; k0 += 32) {
        gload_lds16(gA0 + k0, lA0);
        gload_lds16(gA1 + k0, lA1);
        gload_lds16(gB0 + k0, lB0);
        gload_lds16(gB1 + k0, lB1);
        __syncthreads();
        bf16x8 af[4], bfr[4];
        #pragma unroll
        for (int i = 0; i < 4; i++) {
            af[i]  = *(const bf16x8*)(As + (wr * 64 + i * 16 + fr) * 32 + fko);
            bfr[i] = *(const bf16x8*)(Bs + (wc * 64 + i * 16 + fr) * 32 + fko);
        }
        #pragma unroll
        for (int i = 0; i < 4; i++)
            #pragma unroll
            for (int j = 0; j < 4; j++)
                acc[i][j] = __builtin_amdgcn_mfma_f32_16x16x32_bf16(af[i], bfr[j], acc[i][j], 0, 0, 0);
        __syncthreads();
    }

    const int quad = lane >> 4;
    #pragma unroll
    for (int j = 0; j < 4; j++) {
        const int col = tn + wc * 64 + j * 16 + fr;
        const float bv = bias[col];
        #pragma unroll
        for (int i = 0; i < 4; i++) {
            const int row0 = tm + wr * 64 + i * 16 + quad * 4;
            #pragma unroll
            for (int r = 0; r < 4; r++) {
                float z = acc[i][j][r] + bv;
                const size_t idx = (size_t)(row0 + r) * N + col;
                if constexpr (EPI == 0) {
                    ((float*)outp)[idx] = (z > 20.f) ? z : log1pf(__expf(z));
                } else if constexpr (EPI == 1) {
                    float ge = 0.5f * z * (1.0f + erff(z * 0.70710678118f));
                    ((USHORT*)outp)[idx] = f2bf(ge);
                } else {
                    ((float*)outp)[idx] = z + extra[idx];
                }
            }
        }
    }
}

// ---------------- bc = xn @ Wbc^T + bbc : (4096 x 32), 1 block per token ----
__global__ __launch_bounds__(256)
void bc_kernel(const USHORT* __restrict__ xn, const float* __restrict__ Wbc,
               const float* __restrict__ bbc, float* __restrict__ bc)
{
    const int tok = blockIdx.x;
    const int n = threadIdx.x & 31;
    const int kg = threadIdx.x >> 5;   // 0..7
    const USHORT* xrow = xn + (size_t)tok * 1024 + kg * 128;
    const float* wrow = Wbc + (size_t)n * 1024 + kg * 128;
    float acc = 0.f;
    #pragma unroll 8
    for (int k = 0; k < 128; k += 4) {
        ushort4 xv = *(const ushort4*)(xrow + k);
        float4 wv = *(const float4*)(wrow + k);
        acc += b2f(xv.x) * wv.x + b2f(xv.y) * wv.y
             + b2f(xv.z) * wv.z + b2f(xv.w) * wv.w;
    }
    __shared__ float part[8][32];
    part[kg][n] = acc;
    __syncthreads();
    if (threadIdx.x < 32) {
        float r = bbc[threadIdx.x];
        #pragma unroll
        for (int i = 0; i < 8; i++) r += part[i][threadIdx.x];
        bc[(size_t)tok * 32 + threadIdx.x] = r;
    }
}

// ---------------- selective scan: 1 wave per (b, 4 h's); lane=(h_local, n) --
// ssm_out = x + y + D*xn  (f32 out)
__global__ __launch_bounds__(64)
void scan_kernel(const float* __restrict__ x, const USHORT* __restrict__ xn,
                 const float* __restrict__ delta, const float* __restrict__ bc,
                 const float* __restrict__ Alog, const float* __restrict__ Dp,
                 float* __restrict__ ssm)
{
    const int lane = threadIdx.x;
    const int n = lane & 15;
    const int hl = lane >> 4;
    const int h0 = blockIdx.x * 4;
    const int b = blockIdx.y;
    const float An = -__expf(Alog[(h0 + hl) * 16 + n]);
    float Dv[4];
    #pragma unroll
    for (int j = 0; j < 4; j++) Dv[j] = Dp[h0 + j];

    __shared__ __align__(16) float sB[64][16];
    __shared__ __align__(16) float sC[64][16];
    __shared__ __align__(16) float sDel[64][4];
    __shared__ __align__(16) float sXn[64][4];
    __shared__ __align__(16) float sY[64][4];

    float s = 0.f;
    const size_t tokb = (size_t)b * 2048;
    for (int c = 0; c < 32; ++c) {
        const size_t tok = tokb + c * 64 + lane;   // this thread stages timestep tok
        const float4 dv = *(const float4*)(delta + tok * 1024 + h0);
        const ushort4 xnv = *(const ushort4*)(xn + tok * 1024 + h0);
        const float4 xrv = *(const float4*)(x + tok * 1024 + h0);
        const float4 bm0 = *(const float4*)(bc + tok * 32 + 0);
        const float4 bm1 = *(const float4*)(bc + tok * 32 + 4);
        const float4 bm2 = *(const float4*)(bc + tok * 32 + 8);
        const float4 bm3 = *(const float4*)(bc + tok * 32 + 12);
        const float4 cm0 = *(const float4*)(bc + tok * 32 + 16);
        const float4 cm1 = *(const float4*)(bc + tok * 32 + 20);
        const float4 cm2 = *(const float4*)(bc + tok * 32 + 24);
        const float4 cm3 = *(const float4*)(bc + tok * 32 + 28);
        float xnr[4] = { b2f(xnv.x), b2f(xnv.y), b2f(xnv.z), b2f(xnv.w) };

        __syncthreads();   // previous chunk's LDS consumers done
        sDel[lane][0] = dv.x; sDel[lane][1] = dv.y; sDel[lane][2] = dv.z; sDel[lane][3] = dv.w;
        sXn[lane][0] = xnr[0]; sXn[lane][1] = xnr[1]; sXn[lane][2] = xnr[2]; sXn[lane][3] = xnr[3];
        *(float4*)&sB[lane][0]  = bm0; *(float4*)&sB[lane][4]  = bm1;
        *(float4*)&sB[lane][8]  = bm2; *(float4*)&sB[lane][12] = bm3;
        *(float4*)&sC[lane][0]  = cm0; *(float4*)&sC[lane][4]  = cm1;
        *(float4*)&sC[lane][8]  = cm2; *(float4*)&sC[lane][12] = cm3;
        __syncthreads();

        #pragma unroll 4
        for (int t = 0; t < 64; ++t) {
            const float d = sDel[t][hl];
            const float xv = sXn[t][hl];
            const float dA = __expf(d * An);
            s = fmaf(dA, s, d * sB[t][n] * xv);
            float y = s * sC[t][n];
            y += __shfl_xor(y, 1);
            y += __shfl_xor(y, 2);
            y += __shfl_xor(y, 4);
            y += __shfl_xor(y, 8);
            if (n == 0) sY[t][hl] = y;
        }
        __syncthreads();

        float4 o;
        o.x = xrv.x + sY[lane][0] + Dv[0] * xnr[0];
        o.y = xrv.y + sY[lane][1] + Dv[1] * xnr[1];
        o.z = xrv.z + sY[lane][2] + Dv[2] * xnr[2];
        o.w = xrv.w + sY[lane][3] + Dv[3] * xnr[3];
        *(float4*)(ssm + tok * 1024 + h0) = o;
    }
}

extern "C" void kernel_launch(void* const* d_in, const int* in_sizes, int n_in,
                              void* d_out, int out_size, void* d_ws, size_t ws_size,
                              hipStream_t stream)
{
    const float* x    = (const float*)d_in[0];
    const float* ln1g = (const float*)d_in[1];
    const float* ln1b = (const float*)d_in[2];
    const float* Wd   = (const float*)d_in[3];
    const float* bd   = (const float*)d_in[4];
    const float* Wbc  = (const float*)d_in[5];
    const float* bbc  = (const float*)d_in[6];
    const float* Alog = (const float*)d_in[7];
    const float* Dp   = (const float*)d_in[8];
    const float* ln2g = (const float*)d_in[9];
    const float* ln2b = (const float*)d_in[10];
    const float* W1   = (const float*)d_in[11];
    const float* b1   = (const float*)d_in[12];
    const float* W2   = (const float*)d_in[13];
    const float* b2   = (const float*)d_in[14];
    float* out = (float*)d_out;

    char* ws = (char*)d_ws;
    const size_t MB = 1024 * 1024;
    float*  deltaW = (float*)(ws + 0);            // 16 MiB (4096x1024 f32)
    float*  ssmW   = (float*)(ws + 16 * MB);      // 16 MiB (4096x1024 f32)
    USHORT* xnW    = (USHORT*)(ws + 32 * MB);     //  8 MiB (4096x1024 bf16)
    USHORT* nrmW   = (USHORT*)(ws + 40 * MB);     //  8 MiB (4096x1024 bf16)
    USHORT* hffW   = (USHORT*)(ws + 48 * MB);     // 32 MiB (4096x4096 bf16)
    float*  bcW    = (float*)(ws + 80 * MB);      // 512 KiB (4096x32 f32)
    USHORT* WdB    = (USHORT*)(ws + 81 * MB);     //  2 MiB (1024x1024 bf16)
    USHORT* W1B    = (USHORT*)(ws + 83 * MB);     //  8 MiB (4096x1024 bf16)
    USHORT* W2B    = (USHORT*)(ws + 91 * MB);     //  8 MiB (1024x4096 bf16)

    // 0. convert weights f32 -> bf16
    f2b_kernel<<<1024, 256, 0, stream>>>(Wd, WdB, 1024 * 1024);
    f2b_kernel<<<4096, 256, 0, stream>>>(W1, W1B, 4096 * 1024);
    f2b_kernel<<<4096, 256, 0, stream>>>(W2, W2B, 1024 * 4096);
    // 1. xn = LN1(x)                         (bf16)
    ln_kernel<<<4096, 256, 0, stream>>>(x, ln1g, ln1b, xnW);
    // 2. delta = softplus(xn @ Wd^T + bd)    (f32)
    gemm_bt<0><<<dim3(8, 32), 256, 0, stream>>>(xnW, WdB, bd, nullptr, deltaW, 4096, 1024, 1024);
    // 3. bc = xn @ Wbc^T + bbc               (f32)
    bc_kernel<<<4096, 256, 0, stream>>>(xnW, Wbc, bbc, bcW);
    // 4. ssm_out = x + scan(...) + D*xn      (f32)
    scan_kernel<<<dim3(256, 2), 64, 0, stream>>>(x, xnW, deltaW, bcW, Alog, Dp, ssmW);
    // 5. normed = LN2(ssm_out)               (bf16)
    ln_kernel<<<4096, 256, 0, stream>>>(ssmW, ln2g, ln2b, nrmW);
    // 6. hff = gelu(normed @ W1^T + b1)      (bf16)
    gemm_bt<1><<<dim3(32, 32), 256, 0, stream>>>(nrmW, W1B, b1, nullptr, hffW, 4096, 4096, 1024);
    // 7. out = hff @ W2^T + b2 + ssm_out     (f32)
    gemm_bt<2><<<dim3(8, 32), 256, 0, stream>>>(hffW, W2B, b2, ssmW, out, 4096, 1024, 4096);

    (void)in_sizes; (void)n_in; (void)out_size; (void)ws_size;
}

// Round 3
// 626.710 us; speedup vs baseline: 1.3117x; 1.3117x over previous
//
#include <hip/hip_runtime.h>
#include <cstdint>
#include <cstddef>

typedef unsigned short USHORT;
typedef __bf16 bf16x8 __attribute__((ext_vector_type(8)));
typedef float f32x4 __attribute__((ext_vector_type(4)));

__device__ __forceinline__ float b2f(USHORT u) {
    union { unsigned int i; float f; } v; v.i = ((unsigned int)u) << 16; return v.f;
}
__device__ __forceinline__ USHORT f2bf(float f) {
    union { float f; unsigned int i; } v; v.f = f;
    unsigned int u = v.i;
    unsigned int r = (u + 0x7FFFu + ((u >> 16) & 1u)) >> 16;
    return (USHORT)r;
}

__device__ __forceinline__ void gload_lds16(const void* g, void* l) {
    __builtin_amdgcn_global_load_lds(
        (const __attribute__((address_space(1))) void*)(uintptr_t)g,
        (__attribute__((address_space(3))) void*)(uint32_t)(uintptr_t)l,
        16, 0, 0);
}

// DPP-based cross-lane add: y + shuffled(y), VALU latency (~4-8cyc) instead of
// ds_permute (~120cyc). CTRL: 0xB1=quad_perm xor1, 0x4E=quad_perm xor2,
// 0x141=row_half_mirror, 0x140=row_mirror. Sequence of the 4 gives each lane
// the sum over its 16-lane row.
template<int CTRL>
__device__ __forceinline__ float dpp_add(float y) {
    int t = __builtin_amdgcn_update_dpp(0, __float_as_int(y), CTRL, 0xF, 0xF, true);
    return y + __int_as_float(t);
}

// ---------------- f32 -> bf16 conversion (weights), 4 elems/thread ----------
__global__ __launch_bounds__(256)
void f2b_kernel(const float* __restrict__ src, USHORT* __restrict__ dst, int n)
{
    int i = (blockIdx.x * 256 + threadIdx.x) * 4;
    if (i < n) {
        float4 v = *(const float4*)(src + i);
        ushort4 o;
        o.x = f2bf(v.x); o.y = f2bf(v.y); o.z = f2bf(v.z); o.w = f2bf(v.w);
        *(ushort4*)(dst + i) = o;
    }
}

// ---------------- LayerNorm: f32 in -> bf16 out. 1 block/token, 256 thr ----
__global__ __launch_bounds__(256)
void ln_kernel(const float* __restrict__ inp, const float* __restrict__ g,
               const float* __restrict__ bsh, USHORT* __restrict__ out)
{
    const int tid = threadIdx.x;
    const size_t row = blockIdx.x;
    float4 t = ((const float4*)inp)[row * 256 + tid];
    float v[4] = { t.x, t.y, t.z, t.w };
    float s = v[0] + v[1] + v[2] + v[3];
    float sq = v[0]*v[0] + v[1]*v[1] + v[2]*v[2] + v[3]*v[3];
    #pragma unroll
    for (int off = 32; off; off >>= 1) { s += __shfl_down(s, off); sq += __shfl_down(sq, off); }
    __shared__ float red[8];
    const int wv = tid >> 6;
    if ((tid & 63) == 0) { red[wv] = s; red[wv + 4] = sq; }
    __syncthreads();
    const float S  = red[0] + red[1] + red[2] + red[3];
    const float SQ = red[4] + red[5] + red[6] + red[7];
    const float mu = S * (1.0f / 1024.0f);
    const float var = SQ * (1.0f / 1024.0f) - mu * mu;
    const float rs = rsqrtf(var + 1e-5f);
    float4 gv = ((const float4*)g)[tid];
    float4 bv = ((const float4*)bsh)[tid];
    ushort4 o;
    o.x = f2bf((v[0] - mu) * rs * gv.x + bv.x);
    o.y = f2bf((v[1] - mu) * rs * gv.y + bv.y);
    o.z = f2bf((v[2] - mu) * rs * gv.z + bv.z);
    o.w = f2bf((v[3] - mu) * rs * gv.w + bv.w);
    ((ushort4*)out)[row * 256 + tid] = o;
}

// ---------------- GEMM: C(M,N) = A(M,K) @ B(N,K)^T, bf16 MFMA, fused epilogue
// EPI 0: softplus -> f32 out; EPI 1: exact gelu -> bf16 out; EPI 2: +extra -> f32 out
template<int EPI>
__global__ __launch_bounds__(256)
void gemm_bt(const USHORT* __restrict__ A, const USHORT* __restrict__ B,
             const float* __restrict__ bias, const float* __restrict__ extra,
             void* __restrict__ outp, int M, int N, int K)
{
    __shared__ __align__(16) USHORT As[128 * 32];
    __shared__ __align__(16) USHORT Bs[128 * 32];
    const int tid = threadIdx.x;
    const int lane = tid & 63;
    const int w = tid >> 6;
    const int wr = w >> 1, wc = w & 1;
    const int tm = blockIdx.y * 128;
    const int tn = blockIdx.x * 128;

    f32x4 acc[4][4];
    #pragma unroll
    for (int i = 0; i < 4; i++)
        #pragma unroll
        for (int j = 0; j < 4; j++) acc[i][j] = (f32x4){0.f, 0.f, 0.f, 0.f};

    const int srow = tid >> 2;          // 0..63
    const int scol = (tid & 3) * 8;     // 0,8,16,24
    const USHORT* gA0 = A + (size_t)(tm + srow) * K + scol;
    const USHORT* gA1 = A + (size_t)(tm + 64 + srow) * K + scol;
    const USHORT* gB0 = B + (size_t)(tn + srow) * K + scol;
    const USHORT* gB1 = B + (size_t)(tn + 64 + srow) * K + scol;
    USHORT* lA0 = As + w * 512;          // wave-uniform LDS bases
    USHORT* lA1 = As + 2048 + w * 512;
    USHORT* lB0 = Bs + w * 512;
    USHORT* lB1 = Bs + 2048 + w * 512;

    const int fr = lane & 15;
    const int fko = (lane >> 4) * 8;

    for (int k0 = 0; k0 < K; k0 += 32) {
        gload_lds16(gA0 + k0, lA0);
        gload_lds16(gA1 + k0, lA1);
        gload_lds16(gB0 + k0, lB0);
        gload_lds16(gB1 + k0, lB1);
        __syncthreads();
        bf16x8 af[4], bfr[4];
        #pragma unroll
        for (int i = 0; i < 4; i++) {
            af[i]  = *(const bf16x8*)(As + (wr * 64 + i * 16 + fr) * 32 + fko);
            bfr[i] = *(const bf16x8*)(Bs + (wc * 64 + i * 16 + fr) * 32 + fko);
        }
        #pragma unroll
        for (int i = 0; i < 4; i++)
            #pragma unroll
            for (int j = 0; j < 4; j++)
                acc[i][j] = __builtin_amdgcn_mfma_f32_16x16x32_bf16(af[i], bfr[j], acc[i][j], 0, 0, 0);
        __syncthreads();
    }

    const int quad = lane >> 4;
    #pragma unroll
    for (int j = 0; j < 4; j++) {
        const int col = tn + wc * 64 + j * 16 + fr;
        const float bv = bias[col];
        #pragma unroll
        for (int i = 0; i < 4; i++) {
            const int row0 = tm + wr * 64 + i * 16 + quad * 4;
            #pragma unroll
            for (int r = 0; r < 4; r++) {
                float z = acc[i][j][r] + bv;
                const size_t idx = (size_t)(row0 + r) * N + col;
                if constexpr (EPI == 0) {
                    ((float*)outp)[idx] = (z > 20.f) ? z : log1pf(__expf(z));
                } else if constexpr (EPI == 1) {
                    float ge = 0.5f * z * (1.0f + erff(z * 0.70710678118f));
                    ((USHORT*)outp)[idx] = f2bf(ge);
                } else {
                    ((float*)outp)[idx] = z + extra[idx];
                }
            }
        }
    }
}

// ---------------- bc = xn @ Wbc^T + bbc : (4096 x 32), 1 block per token ----
__global__ __launch_bounds__(256)
void bc_kernel(const USHORT* __restrict__ xn, const float* __restrict__ Wbc,
               const float* __restrict__ bbc, float* __restrict__ bc)
{
    const int tok = blockIdx.x;
    const int n = threadIdx.x & 31;
    const int kg = threadIdx.x >> 5;   // 0..7
    const USHORT* xrow = xn + (size_t)tok * 1024 + kg * 128;
    const float* wrow = Wbc + (size_t)n * 1024 + kg * 128;
    float acc = 0.f;
    #pragma unroll 8
    for (int k = 0; k < 128; k += 4) {
        ushort4 xv = *(const ushort4*)(xrow + k);
        float4 wv = *(const float4*)(wrow + k);
        acc += b2f(xv.x) * wv.x + b2f(xv.y) * wv.y
             + b2f(xv.z) * wv.z + b2f(xv.w) * wv.w;
    }
    __shared__ float part[8][32];
    part[kg][n] = acc;
    __syncthreads();
    if (threadIdx.x < 32) {
        float r = bbc[threadIdx.x];
        #pragma unroll
        for (int i = 0; i < 8; i++) r += part[i][threadIdx.x];
        bc[(size_t)tok * 32 + threadIdx.x] = r;
    }
}

// ---------------- selective scan v2 ----------------------------------------
// Grid (64, 2): 16 h-channels per block, 256 threads = 4 waves x (4 h x 16 n).
// Per 64-token chunk: cooperative coalesced staging (64B/token rows) -> LDS,
// per-wave recurrence with DPP 16-lane reduction, cooperative coalesced
// output phase. ssm_out = x + y + D*xn (f32).
__global__ __launch_bounds__(256)
void scan_kernel(const float* __restrict__ x, const USHORT* __restrict__ xn,
                 const float* __restrict__ delta, const float* __restrict__ bc,
                 const float* __restrict__ Alog, const float* __restrict__ Dp,
                 float* __restrict__ ssm)
{
    const int tid = threadIdx.x;
    const int lane = tid & 63;
    const int w = tid >> 6;              // wave 0..3
    const int n = lane & 15;
    const int hh = w * 4 + (lane >> 4);  // local h 0..15
    const int h0 = blockIdx.x * 16;
    const int b = blockIdx.y;

    const float An = -__expf(Alog[(h0 + hh) * 16 + n]);

    // staging / output-phase identities
    const int stok = tid >> 2;           // 0..63 (token within chunk)
    const int spart = tid & 3;           // 0..3  (16B part of the 64B row)
    float4 Dv = *(const float4*)(Dp + h0 + spart * 4);

    __shared__ __align__(16) float sDel[64][16];
    __shared__ __align__(16) float sXn[64][16];
    __shared__ __align__(16) float sB[64][16];
    __shared__ __align__(16) float sC[64][16];
    __shared__ __align__(16) float sY[64][16];

    float s = 0.f;
    const size_t tokb = (size_t)b * 2048;
    for (int c = 0; c < 32; ++c) {
        const size_t tok = tokb + c * 64 + stok;
        // issue global loads before the barrier (regs), store to LDS after
        const float4 dv   = *(const float4*)(delta + tok * 1024 + h0 + spart * 4);
        const ushort4 xnv = *(const ushort4*)(xn + tok * 1024 + h0 + spart * 4);
        const float4 bv   = *(const float4*)(bc + tok * 32 + spart * 4);
        const float4 cv   = *(const float4*)(bc + tok * 32 + 16 + spart * 4);

        __syncthreads();   // previous chunk's output phase done with LDS
        *(float4*)&sDel[stok][spart * 4] = dv;
        sXn[stok][spart * 4 + 0] = b2f(xnv.x);
        sXn[stok][spart * 4 + 1] = b2f(xnv.y);
        sXn[stok][spart * 4 + 2] = b2f(xnv.z);
        sXn[stok][spart * 4 + 3] = b2f(xnv.w);
        *(float4*)&sB[stok][spart * 4] = bv;
        *(float4*)&sC[stok][spart * 4] = cv;
        __syncthreads();

        #pragma unroll 8
        for (int t = 0; t < 64; ++t) {
            const float d  = sDel[t][hh];
            const float xv = sXn[t][hh];
            const float bn = sB[t][n];
            const float cn = sC[t][n];
            const float dA = __expf(d * An);
            s = fmaf(dA, s, d * bn * xv);
            float y = s * cn;
            y = dpp_add<0xB1>(y);    // + xor1 (quad_perm 1,0,3,2)
            y = dpp_add<0x4E>(y);    // + xor2 (quad_perm 2,3,0,1)
            y = dpp_add<0x141>(y);   // + row_half_mirror
            y = dpp_add<0x140>(y);   // + row_mirror -> full 16-lane sum
            if (n == 0) sY[t][hh] = y;
        }
        __syncthreads();

        // output phase: coalesced read of x, write of ssm
        const float4 xrv = *(const float4*)(x + tok * 1024 + h0 + spart * 4);
        float4 o;
        o.x = xrv.x + sY[stok][spart * 4 + 0] + Dv.x * sXn[stok][spart * 4 + 0];
        o.y = xrv.y + sY[stok][spart * 4 + 1] + Dv.y * sXn[stok][spart * 4 + 1];
        o.z = xrv.z + sY[stok][spart * 4 + 2] + Dv.z * sXn[stok][spart * 4 + 2];
        o.w = xrv.w + sY[stok][spart * 4 + 3] + Dv.w * sXn[stok][spart * 4 + 3];
        *(float4*)(ssm + tok * 1024 + h0 + spart * 4) = o;
    }
}

extern "C" void kernel_launch(void* const* d_in, const int* in_sizes, int n_in,
                              void* d_out, int out_size, void* d_ws, size_t ws_size,
                              hipStream_t stream)
{
    const float* x    = (const float*)d_in[0];
    const float* ln1g = (const float*)d_in[1];
    const float* ln1b = (const float*)d_in[2];
    const float* Wd   = (const float*)d_in[3];
    const float* bd   = (const float*)d_in[4];
    const float* Wbc  = (const float*)d_in[5];
    const float* bbc  = (const float*)d_in[6];
    const float* Alog = (const float*)d_in[7];
    const float* Dp   = (const float*)d_in[8];
    const float* ln2g = (const float*)d_in[9];
    const float* ln2b = (const float*)d_in[10];
    const float* W1   = (const float*)d_in[11];
    const float* b1   = (const float*)d_in[12];
    const float* W2   = (const float*)d_in[13];
    const float* b2   = (const float*)d_in[14];
    float* out = (float*)d_out;

    char* ws = (char*)d_ws;
    const size_t MB = 1024 * 1024;
    float*  deltaW = (float*)(ws + 0);            // 16 MiB (4096x1024 f32)
    float*  ssmW   = (float*)(ws + 16 * MB);      // 16 MiB (4096x1024 f32)
    USHORT* xnW    = (USHORT*)(ws + 32 * MB);     //  8 MiB (4096x1024 bf16)
    USHORT* nrmW   = (USHORT*)(ws + 40 * MB);     //  8 MiB (4096x1024 bf16)
    USHORT* hffW   = (USHORT*)(ws + 48 * MB);     // 32 MiB (4096x4096 bf16)
    float*  bcW    = (float*)(ws + 80 * MB);      // 512 KiB (4096x32 f32)
    USHORT* WdB    = (USHORT*)(ws + 81 * MB);     //  2 MiB (1024x1024 bf16)
    USHORT* W1B    = (USHORT*)(ws + 83 * MB);     //  8 MiB (4096x1024 bf16)
    USHORT* W2B    = (USHORT*)(ws + 91 * MB);     //  8 MiB (1024x4096 bf16)

    // 0. convert weights f32 -> bf16
    f2b_kernel<<<1024, 256, 0, stream>>>(Wd, WdB, 1024 * 1024);
    f2b_kernel<<<4096, 256, 0, stream>>>(W1, W1B, 4096 * 1024);
    f2b_kernel<<<4096, 256, 0, stream>>>(W2, W2B, 1024 * 4096);
    // 1. xn = LN1(x)                         (bf16)
    ln_kernel<<<4096, 256, 0, stream>>>(x, ln1g, ln1b, xnW);
    // 2. delta = softplus(xn @ Wd^T + bd)    (f32)
    gemm_bt<0><<<dim3(8, 32), 256, 0, stream>>>(xnW, WdB, bd, nullptr, deltaW, 4096, 1024, 1024);
    // 3. bc = xn @ Wbc^T + bbc               (f32)
    bc_kernel<<<4096, 256, 0, stream>>>(xnW, Wbc, bbc, bcW);
    // 4. ssm_out = x + scan(...) + D*xn      (f32)
    scan_kernel<<<dim3(64, 2), 256, 0, stream>>>(x, xnW, deltaW, bcW, Alog, Dp, ssmW);
    // 5. normed = LN2(ssm_out)               (bf16)
    ln_kernel<<<4096, 256, 0, stream>>>(ssmW, ln2g, ln2b, nrmW);
    // 6. hff = gelu(normed @ W1^T + b1)      (bf16)
    gemm_bt<1><<<dim3(32, 32), 256, 0, stream>>>(nrmW, W1B, b1, nullptr, hffW, 4096, 4096, 1024);
    // 7. out = hff @ W2^T + b2 + ssm_out     (f32)
    gemm_bt<2><<<dim3(8, 32), 256, 0, stream>>>(hffW, W2B, b2, ssmW, out, 4096, 1024, 4096);

    (void)in_sizes; (void)n_in; (void)out_size; (void)ws_size;
}

// Round 4
// 459.724 us; speedup vs baseline: 1.7882x; 1.3632x over previous
//
#include <hip/hip_runtime.h>
#include <cstdint>
#include <cstddef>

typedef unsigned short USHORT;
typedef __bf16 bf16x8 __attribute__((ext_vector_type(8)));
typedef float f32x4 __attribute__((ext_vector_type(4)));

__device__ __forceinline__ float b2f(USHORT u) {
    union { unsigned int i; float f; } v; v.i = ((unsigned int)u) << 16; return v.f;
}
__device__ __forceinline__ USHORT f2bf(float f) {
    union { float f; unsigned int i; } v; v.f = f;
    unsigned int u = v.i;
    unsigned int r = (u + 0x7FFFu + ((u >> 16) & 1u)) >> 16;
    return (USHORT)r;
}
__device__ __forceinline__ float fexp2(float x) { return __builtin_amdgcn_exp2f(x); }

__device__ __forceinline__ void gload_lds16(const void* g, void* l) {
    __builtin_amdgcn_global_load_lds(
        (const __attribute__((address_space(1))) void*)(uintptr_t)g,
        (__attribute__((address_space(3))) void*)(uint32_t)(uintptr_t)l,
        16, 0, 0);
}

// ---------------- f32 -> bf16 conversion (weights), 4 elems/thread ----------
__global__ __launch_bounds__(256)
void f2b_kernel(const float* __restrict__ src, USHORT* __restrict__ dst, int n)
{
    int i = (blockIdx.x * 256 + threadIdx.x) * 4;
    if (i < n) {
        float4 v = *(const float4*)(src + i);
        ushort4 o;
        o.x = f2bf(v.x); o.y = f2bf(v.y); o.z = f2bf(v.z); o.w = f2bf(v.w);
        *(ushort4*)(dst + i) = o;
    }
}

// ---------------- LayerNorm: f32 in -> bf16 out. 1 block/token, 256 thr ----
__global__ __launch_bounds__(256)
void ln_kernel(const float* __restrict__ inp, const float* __restrict__ g,
               const float* __restrict__ bsh, USHORT* __restrict__ out)
{
    const int tid = threadIdx.x;
    const size_t row = blockIdx.x;
    float4 t = ((const float4*)inp)[row * 256 + tid];
    float v[4] = { t.x, t.y, t.z, t.w };
    float s = v[0] + v[1] + v[2] + v[3];
    float sq = v[0]*v[0] + v[1]*v[1] + v[2]*v[2] + v[3]*v[3];
    #pragma unroll
    for (int off = 32; off; off >>= 1) { s += __shfl_down(s, off); sq += __shfl_down(sq, off); }
    __shared__ float red[8];
    const int wv = tid >> 6;
    if ((tid & 63) == 0) { red[wv] = s; red[wv + 4] = sq; }
    __syncthreads();
    const float S  = red[0] + red[1] + red[2] + red[3];
    const float SQ = red[4] + red[5] + red[6] + red[7];
    const float mu = S * (1.0f / 1024.0f);
    const float var = SQ * (1.0f / 1024.0f) - mu * mu;
    const float rs = rsqrtf(var + 1e-5f);
    float4 gv = ((const float4*)g)[tid];
    float4 bv = ((const float4*)bsh)[tid];
    ushort4 o;
    o.x = f2bf((v[0] - mu) * rs * gv.x + bv.x);
    o.y = f2bf((v[1] - mu) * rs * gv.y + bv.y);
    o.z = f2bf((v[2] - mu) * rs * gv.z + bv.z);
    o.w = f2bf((v[3] - mu) * rs * gv.w + bv.w);
    ((ushort4*)out)[row * 256 + tid] = o;
}

// ---------------- GEMM: C(M,N) = A(M,K) @ B(N,K)^T, bf16 MFMA, fused epilogue
// EPI 0: softplus -> f32 out; EPI 1: exact gelu -> bf16 out; EPI 2: +extra -> f32 out
template<int EPI>
__global__ __launch_bounds__(256)
void gemm_bt(const USHORT* __restrict__ A, const USHORT* __restrict__ B,
             const float* __restrict__ bias, const float* __restrict__ extra,
             void* __restrict__ outp, int M, int N, int K)
{
    __shared__ __align__(16) USHORT As[128 * 32];
    __shared__ __align__(16) USHORT Bs[128 * 32];
    const int tid = threadIdx.x;
    const int lane = tid & 63;
    const int w = tid >> 6;
    const int wr = w >> 1, wc = w & 1;
    const int tm = blockIdx.y * 128;
    const int tn = blockIdx.x * 128;

    f32x4 acc[4][4];
    #pragma unroll
    for (int i = 0; i < 4; i++)
        #pragma unroll
        for (int j = 0; j < 4; j++) acc[i][j] = (f32x4){0.f, 0.f, 0.f, 0.f};

    const int srow = tid >> 2;          // 0..63
    const int scol = (tid & 3) * 8;     // 0,8,16,24
    const USHORT* gA0 = A + (size_t)(tm + srow) * K + scol;
    const USHORT* gA1 = A + (size_t)(tm + 64 + srow) * K + scol;
    const USHORT* gB0 = B + (size_t)(tn + srow) * K + scol;
    const USHORT* gB1 = B + (size_t)(tn + 64 + srow) * K + scol;
    USHORT* lA0 = As + w * 512;          // wave-uniform LDS bases
    USHORT* lA1 = As + 2048 + w * 512;
    USHORT* lB0 = Bs + w * 512;
    USHORT* lB1 = Bs + 2048 + w * 512;

    const int fr = lane & 15;
    const int fko = (lane >> 4) * 8;

    for (int k0 = 0; k0 < K; k0 += 32) {
        gload_lds16(gA0 + k0, lA0);
        gload_lds16(gA1 + k0, lA1);
        gload_lds16(gB0 + k0, lB0);
        gload_lds16(gB1 + k0, lB1);
        __syncthreads();
        bf16x8 af[4], bfr[4];
        #pragma unroll
        for (int i = 0; i < 4; i++) {
            af[i]  = *(const bf16x8*)(As + (wr * 64 + i * 16 + fr) * 32 + fko);
            bfr[i] = *(const bf16x8*)(Bs + (wc * 64 + i * 16 + fr) * 32 + fko);
        }
        #pragma unroll
        for (int i = 0; i < 4; i++)
            #pragma unroll
            for (int j = 0; j < 4; j++)
                acc[i][j] = __builtin_amdgcn_mfma_f32_16x16x32_bf16(af[i], bfr[j], acc[i][j], 0, 0, 0);
        __syncthreads();
    }

    const int quad = lane >> 4;
    #pragma unroll
    for (int j = 0; j < 4; j++) {
        const int col = tn + wc * 64 + j * 16 + fr;
        const float bv = bias[col];
        #pragma unroll
        for (int i = 0; i < 4; i++) {
            const int row0 = tm + wr * 64 + i * 16 + quad * 4;
            #pragma unroll
            for (int r = 0; r < 4; r++) {
                float z = acc[i][j][r] + bv;
                const size_t idx = (size_t)(row0 + r) * N + col;
                if constexpr (EPI == 0) {
                    ((float*)outp)[idx] = (z > 20.f) ? z : log1pf(__expf(z));
                } else if constexpr (EPI == 1) {
                    float ge = 0.5f * z * (1.0f + erff(z * 0.70710678118f));
                    ((USHORT*)outp)[idx] = f2bf(ge);
                } else {
                    ((float*)outp)[idx] = z + extra[idx];
                }
            }
        }
    }
}

// ---------------- bc = xn @ Wbc^T + bbc : (4096 x 32), 1 block per token ----
__global__ __launch_bounds__(256)
void bc_kernel(const USHORT* __restrict__ xn, const float* __restrict__ Wbc,
               const float* __restrict__ bbc, float* __restrict__ bc)
{
    const int tok = blockIdx.x;
    const int n = threadIdx.x & 31;
    const int kg = threadIdx.x >> 5;   // 0..7
    const USHORT* xrow = xn + (size_t)tok * 1024 + kg * 128;
    const float* wrow = Wbc + (size_t)n * 1024 + kg * 128;
    float acc = 0.f;
    #pragma unroll 8
    for (int k = 0; k < 128; k += 4) {
        ushort4 xv = *(const ushort4*)(xrow + k);
        float4 wv = *(const float4*)(wrow + k);
        acc += b2f(xv.x) * wv.x + b2f(xv.y) * wv.y
             + b2f(xv.z) * wv.z + b2f(xv.w) * wv.w;
    }
    __shared__ float part[8][32];
    part[kg][n] = acc;
    __syncthreads();
    if (threadIdx.x < 32) {
        float r = bbc[threadIdx.x];
        #pragma unroll
        for (int i = 0; i < 8; i++) r += part[i][threadIdx.x];
        bc[(size_t)tok * 32 + threadIdx.x] = r;
    }
}

// ---------------- selective scan v3: chunked parallel, lane=h, n in regs ----
// P=64 chunks of T=32 tokens. s recurrence is linear: chunk-local scans in
// parallel (pass1), serial chunk-chaining per (b,h,n) (mid), recompute with
// correct s_in + emit y (pass2). dA[n] = exp2(d * en[n]), en = -exp(Alog)*log2e.
#define SCAN_P 64
#define SCAN_T 32

__global__ __launch_bounds__(256)
void scan_pass1(const USHORT* __restrict__ xn, const float* __restrict__ delta,
                const float* __restrict__ bc, const float* __restrict__ Alog,
                float* __restrict__ sEnd, float* __restrict__ Ptot)
{
    const int tid = threadIdx.x;
    const int h = blockIdx.x * 256 + tid;
    const int b = blockIdx.y;
    const int p = blockIdx.z;
    const size_t tok0 = (size_t)b * 2048 + p * SCAN_T;

    __shared__ __align__(16) float sBC[SCAN_T][32];
    {
        int t = tid >> 3, q = (tid & 7) * 4;
        *(float4*)&sBC[t][q] = *(const float4*)(bc + (tok0 + t) * 32 + q);
    }

    float en[16], s[16], P[16];
    #pragma unroll
    for (int k = 0; k < 4; k++) {
        float4 a = *(const float4*)(Alog + h * 16 + k * 4);
        en[k*4+0] = -__expf(a.x) * 1.44269504f;
        en[k*4+1] = -__expf(a.y) * 1.44269504f;
        en[k*4+2] = -__expf(a.z) * 1.44269504f;
        en[k*4+3] = -__expf(a.w) * 1.44269504f;
    }
    #pragma unroll
    for (int n = 0; n < 16; n++) { s[n] = 0.f; P[n] = 1.f; }
    __syncthreads();

    const float* dp = delta + tok0 * 1024 + h;
    const USHORT* xp = xn + tok0 * 1024 + h;
    float d_c = dp[0];
    USHORT x_c = xp[0];
    for (int t = 0; t < SCAN_T; ++t) {
        const int tn = (t < SCAN_T - 1) ? t + 1 : t;
        float d_n = dp[(size_t)tn * 1024];
        USHORT x_n = xp[(size_t)tn * 1024];
        const float dx = d_c * b2f(x_c);
        #pragma unroll
        for (int k = 0; k < 4; k++) {
            float4 Bv = *(const float4*)&sBC[t][k*4];
            float bb[4] = { Bv.x, Bv.y, Bv.z, Bv.w };
            #pragma unroll
            for (int j = 0; j < 4; j++) {
                const int n = k*4 + j;
                const float dA = fexp2(d_c * en[n]);
                s[n] = fmaf(dA, s[n], dx * bb[j]);
                P[n] *= dA;
            }
        }
        d_c = d_n; x_c = x_n;
    }

    const size_t off = (size_t)p * 32768 + ((size_t)b * 1024 + h) * 16;
    #pragma unroll
    for (int k = 0; k < 4; k++) {
        *(float4*)(sEnd + off + k*4) = (float4){ s[k*4], s[k*4+1], s[k*4+2], s[k*4+3] };
        *(float4*)(Ptot + off + k*4) = (float4){ P[k*4], P[k*4+1], P[k*4+2], P[k*4+3] };
    }
}

__global__ __launch_bounds__(256)
void scan_mid(const float* __restrict__ sEnd, const float* __restrict__ Ptot,
              float* __restrict__ sIn)
{
    const int L = blockIdx.x * 256 + threadIdx.x;   // 0..32767 = (b*1024+h)*16+n
    float s = 0.f;
    #pragma unroll 8
    for (int p = 0; p < SCAN_P; ++p) {
        const size_t off = (size_t)p * 32768 + L;
        sIn[off] = s;
        s = fmaf(Ptot[off], s, sEnd[off]);
    }
}

__global__ __launch_bounds__(256)
void scan_pass2(const float* __restrict__ x, const USHORT* __restrict__ xn,
                const float* __restrict__ delta, const float* __restrict__ bc,
                const float* __restrict__ Alog, const float* __restrict__ Dp,
                const float* __restrict__ sIn, float* __restrict__ ssm)
{
    const int tid = threadIdx.x;
    const int h = blockIdx.x * 256 + tid;
    const int b = blockIdx.y;
    const int p = blockIdx.z;
    const size_t tok0 = (size_t)b * 2048 + p * SCAN_T;

    __shared__ __align__(16) float sBC[SCAN_T][32];
    {
        int t = tid >> 3, q = (tid & 7) * 4;
        *(float4*)&sBC[t][q] = *(const float4*)(bc + (tok0 + t) * 32 + q);
    }

    float en[16], s[16];
    #pragma unroll
    for (int k = 0; k < 4; k++) {
        float4 a = *(const float4*)(Alog + h * 16 + k * 4);
        en[k*4+0] = -__expf(a.x) * 1.44269504f;
        en[k*4+1] = -__expf(a.y) * 1.44269504f;
        en[k*4+2] = -__expf(a.z) * 1.44269504f;
        en[k*4+3] = -__expf(a.w) * 1.44269504f;
    }
    const size_t off = (size_t)p * 32768 + ((size_t)b * 1024 + h) * 16;
    #pragma unroll
    for (int k = 0; k < 4; k++) {
        float4 v = *(const float4*)(sIn + off + k*4);
        s[k*4] = v.x; s[k*4+1] = v.y; s[k*4+2] = v.z; s[k*4+3] = v.w;
    }
    const float Dv = Dp[h];
    __syncthreads();

    const float* dp = delta + tok0 * 1024 + h;
    const USHORT* xp = xn + tok0 * 1024 + h;
    const float* xrp = x + tok0 * 1024 + h;
    float* op = ssm + tok0 * 1024 + h;

    float d_c = dp[0];
    USHORT x_c = xp[0];
    float xr_c = xrp[0];
    for (int t = 0; t < SCAN_T; ++t) {
        const int tn = (t < SCAN_T - 1) ? t + 1 : t;
        float d_n = dp[(size_t)tn * 1024];
        USHORT x_n = xp[(size_t)tn * 1024];
        float xr_n = xrp[(size_t)tn * 1024];
        const float xv = b2f(x_c);
        const float dx = d_c * xv;
        float y = 0.f;
        #pragma unroll
        for (int k = 0; k < 4; k++) {
            float4 Bv = *(const float4*)&sBC[t][k*4];
            float4 Cv = *(const float4*)&sBC[t][16 + k*4];
            float bb[4] = { Bv.x, Bv.y, Bv.z, Bv.w };
            float cc[4] = { Cv.x, Cv.y, Cv.z, Cv.w };
            #pragma unroll
            for (int j = 0; j < 4; j++) {
                const int n = k*4 + j;
                const float dA = fexp2(d_c * en[n]);
                s[n] = fmaf(dA, s[n], dx * bb[j]);
                y = fmaf(cc[j], s[n], y);
            }
        }
        op[(size_t)t * 1024] = xr_c + y + Dv * xv;
        d_c = d_n; x_c = x_n; xr_c = xr_n;
    }
}

extern "C" void kernel_launch(void* const* d_in, const int* in_sizes, int n_in,
                              void* d_out, int out_size, void* d_ws, size_t ws_size,
                              hipStream_t stream)
{
    const float* x    = (const float*)d_in[0];
    const float* ln1g = (const float*)d_in[1];
    const float* ln1b = (const float*)d_in[2];
    const float* Wd   = (const float*)d_in[3];
    const float* bd   = (const float*)d_in[4];
    const float* Wbc  = (const float*)d_in[5];
    const float* bbc  = (const float*)d_in[6];
    const float* Alog = (const float*)d_in[7];
    const float* Dp   = (const float*)d_in[8];
    const float* ln2g = (const float*)d_in[9];
    const float* ln2b = (const float*)d_in[10];
    const float* W1   = (const float*)d_in[11];
    const float* b1   = (const float*)d_in[12];
    const float* W2   = (const float*)d_in[13];
    const float* b2   = (const float*)d_in[14];
    float* out = (float*)d_out;

    char* ws = (char*)d_ws;
    const size_t MB = 1024 * 1024;
    float*  deltaW = (float*)(ws + 0);            // 16 MiB (4096x1024 f32)
    float*  ssmW   = (float*)(ws + 16 * MB);      // 16 MiB (4096x1024 f32)
    USHORT* xnW    = (USHORT*)(ws + 32 * MB);     //  8 MiB (4096x1024 bf16)
    USHORT* nrmW   = (USHORT*)(ws + 40 * MB);     //  8 MiB (4096x1024 bf16)
    USHORT* hffW   = (USHORT*)(ws + 48 * MB);     // 32 MiB (4096x4096 bf16)
    float*  bcW    = (float*)(ws + 80 * MB);      // 512 KiB (4096x32 f32)
    USHORT* WdB    = (USHORT*)(ws + 81 * MB);     //  2 MiB (1024x1024 bf16)
    USHORT* W1B    = (USHORT*)(ws + 83 * MB);     //  8 MiB (4096x1024 bf16)
    USHORT* W2B    = (USHORT*)(ws + 91 * MB);     //  8 MiB (1024x4096 bf16)
    // scan scratch aliases hffW (dead until step 6): 3 x 8 MiB
    float*  sEndW  = (float*)(ws + 48 * MB);
    float*  PtotW  = (float*)(ws + 56 * MB);
    float*  sInW   = (float*)(ws + 64 * MB);

    // 0. convert weights f32 -> bf16
    f2b_kernel<<<1024, 256, 0, stream>>>(Wd, WdB, 1024 * 1024);
    f2b_kernel<<<4096, 256, 0, stream>>>(W1, W1B, 4096 * 1024);
    f2b_kernel<<<4096, 256, 0, stream>>>(W2, W2B, 1024 * 4096);
    // 1. xn = LN1(x)                         (bf16)
    ln_kernel<<<4096, 256, 0, stream>>>(x, ln1g, ln1b, xnW);
    // 2. delta = softplus(xn @ Wd^T + bd)    (f32)
    gemm_bt<0><<<dim3(8, 32), 256, 0, stream>>>(xnW, WdB, bd, nullptr, deltaW, 4096, 1024, 1024);
    // 3. bc = xn @ Wbc^T + bbc               (f32)
    bc_kernel<<<4096, 256, 0, stream>>>(xnW, Wbc, bbc, bcW);
    // 4. ssm_out = x + scan(...) + D*xn      (f32), chunked parallel scan
    scan_pass1<<<dim3(4, 2, SCAN_P), 256, 0, stream>>>(xnW, deltaW, bcW, Alog, sEndW, PtotW);
    scan_mid<<<128, 256, 0, stream>>>(sEndW, PtotW, sInW);
    scan_pass2<<<dim3(4, 2, SCAN_P), 256, 0, stream>>>(x, xnW, deltaW, bcW, Alog, Dp, sInW, ssmW);
    // 5. normed = LN2(ssm_out)               (bf16)
    ln_kernel<<<4096, 256, 0, stream>>>(ssmW, ln2g, ln2b, nrmW);
    // 6. hff = gelu(normed @ W1^T + b1)      (bf16)
    gemm_bt<1><<<dim3(32, 32), 256, 0, stream>>>(nrmW, W1B, b1, nullptr, hffW, 4096, 4096, 1024);
    // 7. out = hff @ W2^T + b2 + ssm_out     (f32)
    gemm_bt<2><<<dim3(8, 32), 256, 0, stream>>>(hffW, W2B, b2, ssmW, out, 4096, 1024, 4096);

    (void)in_sizes; (void)n_in; (void)out_size; (void)ws_size;
}

// Round 5
// 445.821 us; speedup vs baseline: 1.8439x; 1.0312x over previous
//
#include <hip/hip_runtime.h>
#include <cstdint>
#include <cstddef>

typedef unsigned short USHORT;
typedef __bf16 bf16x8 __attribute__((ext_vector_type(8)));
typedef float f32x4 __attribute__((ext_vector_type(4)));

__device__ __forceinline__ float b2f(USHORT u) {
    union { unsigned int i; float f; } v; v.i = ((unsigned int)u) << 16; return v.f;
}
__device__ __forceinline__ USHORT f2bf(float f) {
    union { float f; unsigned int i; } v; v.f = f;
    unsigned int u = v.i;
    unsigned int r = (u + 0x7FFFu + ((u >> 16) & 1u)) >> 16;
    return (USHORT)r;
}
__device__ __forceinline__ float fexp2(float x) { return __builtin_amdgcn_exp2f(x); }

__device__ __forceinline__ void gload_lds16(const void* g, void* l) {
    __builtin_amdgcn_global_load_lds(
        (const __attribute__((address_space(1))) void*)(uintptr_t)g,
        (__attribute__((address_space(3))) void*)(uint32_t)(uintptr_t)l,
        16, 0, 0);
}

// ---------------- f32 -> bf16 conversion (weights), 4 elems/thread ----------
__global__ __launch_bounds__(256)
void f2b_kernel(const float* __restrict__ src, USHORT* __restrict__ dst, int n)
{
    int i = (blockIdx.x * 256 + threadIdx.x) * 4;
    if (i < n) {
        float4 v = *(const float4*)(src + i);
        ushort4 o;
        o.x = f2bf(v.x); o.y = f2bf(v.y); o.z = f2bf(v.z); o.w = f2bf(v.w);
        *(ushort4*)(dst + i) = o;
    }
}

// ---------------- LayerNorm: f32 in -> bf16 out. 1 block/token, 256 thr ----
__global__ __launch_bounds__(256)
void ln_kernel(const float* __restrict__ inp, const float* __restrict__ g,
               const float* __restrict__ bsh, USHORT* __restrict__ out)
{
    const int tid = threadIdx.x;
    const size_t row = blockIdx.x;
    float4 t = ((const float4*)inp)[row * 256 + tid];
    float v[4] = { t.x, t.y, t.z, t.w };
    float s = v[0] + v[1] + v[2] + v[3];
    float sq = v[0]*v[0] + v[1]*v[1] + v[2]*v[2] + v[3]*v[3];
    #pragma unroll
    for (int off = 32; off; off >>= 1) { s += __shfl_down(s, off); sq += __shfl_down(sq, off); }
    __shared__ float red[8];
    const int wv = tid >> 6;
    if ((tid & 63) == 0) { red[wv] = s; red[wv + 4] = sq; }
    __syncthreads();
    const float S  = red[0] + red[1] + red[2] + red[3];
    const float SQ = red[4] + red[5] + red[6] + red[7];
    const float mu = S * (1.0f / 1024.0f);
    const float var = SQ * (1.0f / 1024.0f) - mu * mu;
    const float rs = rsqrtf(var + 1e-5f);
    float4 gv = ((const float4*)g)[tid];
    float4 bv = ((const float4*)bsh)[tid];
    ushort4 o;
    o.x = f2bf((v[0] - mu) * rs * gv.x + bv.x);
    o.y = f2bf((v[1] - mu) * rs * gv.y + bv.y);
    o.z = f2bf((v[2] - mu) * rs * gv.z + bv.z);
    o.w = f2bf((v[3] - mu) * rs * gv.w + bv.w);
    ((ushort4*)out)[row * 256 + tid] = o;
}

// ---------------- GEMM: C(M,N) = A(M,K) @ B(N,K)^T, bf16 MFMA, fused epilogue
// EPI 0: softplus -> f32 out
// EPI 1: exact gelu -> bf16 out
// EPI 3: split-K partial (blockIdx.z selects K-slice), raw bf16 partial out
//        partial z lives at (z<2 ? outp : outp2) + (z&1)*M*N
template<int EPI>
__global__ __launch_bounds__(256)
void gemm_bt(const USHORT* __restrict__ A, const USHORT* __restrict__ B,
             const float* __restrict__ bias, void* __restrict__ outp,
             void* __restrict__ outp2, int M, int N, int K, int lda, int ldb)
{
    __shared__ __align__(16) USHORT As[128 * 32];
    __shared__ __align__(16) USHORT Bs[128 * 32];
    const int tid = threadIdx.x;
    const int lane = tid & 63;
    const int w = tid >> 6;
    const int wr = w >> 1, wc = w & 1;
    const int tm = blockIdx.y * 128;
    const int tn = blockIdx.x * 128;

    USHORT* po = nullptr;
    if constexpr (EPI == 3) {
        const int z = blockIdx.z;
        A += (size_t)z * K;             // K-slice offset within row (lda=full K)
        B += (size_t)z * K;
        po = ((z < 2) ? (USHORT*)outp : (USHORT*)outp2) + (size_t)(z & 1) * M * N;
    }

    f32x4 acc[4][4];
    #pragma unroll
    for (int i = 0; i < 4; i++)
        #pragma unroll
        for (int j = 0; j < 4; j++) acc[i][j] = (f32x4){0.f, 0.f, 0.f, 0.f};

    const int srow = tid >> 2;          // 0..63
    const int scol = (tid & 3) * 8;     // 0,8,16,24
    const USHORT* gA0 = A + (size_t)(tm + srow) * lda + scol;
    const USHORT* gA1 = A + (size_t)(tm + 64 + srow) * lda + scol;
    const USHORT* gB0 = B + (size_t)(tn + srow) * ldb + scol;
    const USHORT* gB1 = B + (size_t)(tn + 64 + srow) * ldb + scol;
    USHORT* lA0 = As + w * 512;          // wave-uniform LDS bases
    USHORT* lA1 = As + 2048 + w * 512;
    USHORT* lB0 = Bs + w * 512;
    USHORT* lB1 = Bs + 2048 + w * 512;

    const int fr = lane & 15;
    const int fko = (lane >> 4) * 8;

    for (int k0 = 0; k0 < K; k0 += 32) {
        gload_lds16(gA0 + k0, lA0);
        gload_lds16(gA1 + k0, lA1);
        gload_lds16(gB0 + k0, lB0);
        gload_lds16(gB1 + k0, lB1);
        __syncthreads();
        bf16x8 af[4], bfr[4];
        #pragma unroll
        for (int i = 0; i < 4; i++) {
            af[i]  = *(const bf16x8*)(As + (wr * 64 + i * 16 + fr) * 32 + fko);
            bfr[i] = *(const bf16x8*)(Bs + (wc * 64 + i * 16 + fr) * 32 + fko);
        }
        #pragma unroll
        for (int i = 0; i < 4; i++)
            #pragma unroll
            for (int j = 0; j < 4; j++)
                acc[i][j] = __builtin_amdgcn_mfma_f32_16x16x32_bf16(af[i], bfr[j], acc[i][j], 0, 0, 0);
        __syncthreads();
    }

    const int quad = lane >> 4;
    #pragma unroll
    for (int j = 0; j < 4; j++) {
        const int col = tn + wc * 64 + j * 16 + fr;
        const float bv = (EPI == 3) ? 0.f : bias[col];
        #pragma unroll
        for (int i = 0; i < 4; i++) {
            const int row0 = tm + wr * 64 + i * 16 + quad * 4;
            #pragma unroll
            for (int r = 0; r < 4; r++) {
                float z = acc[i][j][r] + bv;
                const size_t idx = (size_t)(row0 + r) * N + col;
                if constexpr (EPI == 0) {
                    ((float*)outp)[idx] = (z > 20.f) ? z : log1pf(__expf(z));
                } else if constexpr (EPI == 1) {
                    float ge = 0.5f * z * (1.0f + erff(z * 0.70710678118f));
                    ((USHORT*)outp)[idx] = f2bf(ge);
                } else {
                    po[idx] = f2bf(z);
                }
            }
        }
    }
}

// ---------------- FFN2 split-K reduce: out = sum(partials) + bias + extra ---
__global__ __launch_bounds__(256)
void ffn2_reduce(const USHORT* __restrict__ p01, const USHORT* __restrict__ p23,
                 const float* __restrict__ bias, const float* __restrict__ extra,
                 float* __restrict__ out)
{
    const size_t PS = (size_t)4096 * 1024;      // one partial, elems
    const size_t i = ((size_t)blockIdx.x * 256 + threadIdx.x) * 4;
    ushort4 a = *(const ushort4*)(p01 + i);
    ushort4 b = *(const ushort4*)(p01 + PS + i);
    ushort4 c = *(const ushort4*)(p23 + i);
    ushort4 d = *(const ushort4*)(p23 + PS + i);
    float4 bv = *(const float4*)(bias + (i & 1023));
    float4 ev = *(const float4*)(extra + i);
    float4 o;
    o.x = b2f(a.x) + b2f(b.x) + b2f(c.x) + b2f(d.x) + bv.x + ev.x;
    o.y = b2f(a.y) + b2f(b.y) + b2f(c.y) + b2f(d.y) + bv.y + ev.y;
    o.z = b2f(a.z) + b2f(b.z) + b2f(c.z) + b2f(d.z) + bv.z + ev.z;
    o.w = b2f(a.w) + b2f(b.w) + b2f(c.w) + b2f(d.w) + bv.w + ev.w;
    *(float4*)(out + i) = o;
}

// ---------------- bc = xn @ Wbc^T + bbc : (4096 x 32), 1 block per token ----
__global__ __launch_bounds__(256)
void bc_kernel(const USHORT* __restrict__ xn, const float* __restrict__ Wbc,
               const float* __restrict__ bbc, float* __restrict__ bc)
{
    const int tok = blockIdx.x;
    const int n = threadIdx.x & 31;
    const int kg = threadIdx.x >> 5;   // 0..7
    const USHORT* xrow = xn + (size_t)tok * 1024 + kg * 128;
    const float* wrow = Wbc + (size_t)n * 1024 + kg * 128;
    float acc = 0.f;
    #pragma unroll 8
    for (int k = 0; k < 128; k += 4) {
        ushort4 xv = *(const ushort4*)(xrow + k);
        float4 wv = *(const float4*)(wrow + k);
        acc += b2f(xv.x) * wv.x + b2f(xv.y) * wv.y
             + b2f(xv.z) * wv.z + b2f(xv.w) * wv.w;
    }
    __shared__ float part[8][32];
    part[kg][n] = acc;
    __syncthreads();
    if (threadIdx.x < 32) {
        float r = bbc[threadIdx.x];
        #pragma unroll
        for (int i = 0; i < 8; i++) r += part[i][threadIdx.x];
        bc[(size_t)tok * 32 + threadIdx.x] = r;
    }
}

// ---------------- selective scan v3: chunked parallel, lane=h, n in regs ----
#define SCAN_P 64
#define SCAN_T 32

__global__ __launch_bounds__(256)
void scan_pass1(const USHORT* __restrict__ xn, const float* __restrict__ delta,
                const float* __restrict__ bc, const float* __restrict__ Alog,
                float* __restrict__ sEnd, float* __restrict__ Ptot)
{
    const int tid = threadIdx.x;
    const int h = blockIdx.x * 256 + tid;
    const int b = blockIdx.y;
    const int p = blockIdx.z;
    const size_t tok0 = (size_t)b * 2048 + p * SCAN_T;

    __shared__ __align__(16) float sBC[SCAN_T][32];
    {
        int t = tid >> 3, q = (tid & 7) * 4;
        *(float4*)&sBC[t][q] = *(const float4*)(bc + (tok0 + t) * 32 + q);
    }

    float en[16], s[16], P[16];
    #pragma unroll
    for (int k = 0; k < 4; k++) {
        float4 a = *(const float4*)(Alog + h * 16 + k * 4);
        en[k*4+0] = -__expf(a.x) * 1.44269504f;
        en[k*4+1] = -__expf(a.y) * 1.44269504f;
        en[k*4+2] = -__expf(a.z) * 1.44269504f;
        en[k*4+3] = -__expf(a.w) * 1.44269504f;
    }
    #pragma unroll
    for (int n = 0; n < 16; n++) { s[n] = 0.f; P[n] = 1.f; }
    __syncthreads();

    const float* dp = delta + tok0 * 1024 + h;
    const USHORT* xp = xn + tok0 * 1024 + h;
    float d_c = dp[0];
    USHORT x_c = xp[0];
    for (int t = 0; t < SCAN_T; ++t) {
        const int tn = (t < SCAN_T - 1) ? t + 1 : t;
        float d_n = dp[(size_t)tn * 1024];
        USHORT x_n = xp[(size_t)tn * 1024];
        const float dx = d_c * b2f(x_c);
        #pragma unroll
        for (int k = 0; k < 4; k++) {
            float4 Bv = *(const float4*)&sBC[t][k*4];
            float bb[4] = { Bv.x, Bv.y, Bv.z, Bv.w };
            #pragma unroll
            for (int j = 0; j < 4; j++) {
                const int n = k*4 + j;
                const float dA = fexp2(d_c * en[n]);
                s[n] = fmaf(dA, s[n], dx * bb[j]);
                P[n] *= dA;
            }
        }
        d_c = d_n; x_c = x_n;
    }

    const size_t off = (size_t)p * 32768 + ((size_t)b * 1024 + h) * 16;
    #pragma unroll
    for (int k = 0; k < 4; k++) {
        *(float4*)(sEnd + off + k*4) = (float4){ s[k*4], s[k*4+1], s[k*4+2], s[k*4+3] };
        *(float4*)(Ptot + off + k*4) = (float4){ P[k*4], P[k*4+1], P[k*4+2], P[k*4+3] };
    }
}

__global__ __launch_bounds__(256)
void scan_mid(const float* __restrict__ sEnd, const float* __restrict__ Ptot,
              float* __restrict__ sIn)
{
    const int L = blockIdx.x * 256 + threadIdx.x;   // 0..32767 = (b*1024+h)*16+n
    float s = 0.f;
    #pragma unroll 8
    for (int p = 0; p < SCAN_P; ++p) {
        const size_t off = (size_t)p * 32768 + L;
        sIn[off] = s;
        s = fmaf(Ptot[off], s, sEnd[off]);
    }
}

__global__ __launch_bounds__(256)
void scan_pass2(const float* __restrict__ x, const USHORT* __restrict__ xn,
                const float* __restrict__ delta, const float* __restrict__ bc,
                const float* __restrict__ Alog, const float* __restrict__ Dp,
                const float* __restrict__ sIn, float* __restrict__ ssm)
{
    const int tid = threadIdx.x;
    const int h = blockIdx.x * 256 + tid;
    const int b = blockIdx.y;
    const int p = blockIdx.z;
    const size_t tok0 = (size_t)b * 2048 + p * SCAN_T;

    __shared__ __align__(16) float sBC[SCAN_T][32];
    {
        int t = tid >> 3, q = (tid & 7) * 4;
        *(float4*)&sBC[t][q] = *(const float4*)(bc + (tok0 + t) * 32 + q);
    }

    float en[16], s[16];
    #pragma unroll
    for (int k = 0; k < 4; k++) {
        float4 a = *(const float4*)(Alog + h * 16 + k * 4);
        en[k*4+0] = -__expf(a.x) * 1.44269504f;
        en[k*4+1] = -__expf(a.y) * 1.44269504f;
        en[k*4+2] = -__expf(a.z) * 1.44269504f;
        en[k*4+3] = -__expf(a.w) * 1.44269504f;
    }
    const size_t off = (size_t)p * 32768 + ((size_t)b * 1024 + h) * 16;
    #pragma unroll
    for (int k = 0; k < 4; k++) {
        float4 v = *(const float4*)(sIn + off + k*4);
        s[k*4] = v.x; s[k*4+1] = v.y; s[k*4+2] = v.z; s[k*4+3] = v.w;
    }
    const float Dv = Dp[h];
    __syncthreads();

    const float* dp = delta + tok0 * 1024 + h;
    const USHORT* xp = xn + tok0 * 1024 + h;
    const float* xrp = x + tok0 * 1024 + h;
    float* op = ssm + tok0 * 1024 + h;

    float d_c = dp[0];
    USHORT x_c = xp[0];
    float xr_c = xrp[0];
    for (int t = 0; t < SCAN_T; ++t) {
        const int tn = (t < SCAN_T - 1) ? t + 1 : t;
        float d_n = dp[(size_t)tn * 1024];
        USHORT x_n = xp[(size_t)tn * 1024];
        float xr_n = xrp[(size_t)tn * 1024];
        const float xv = b2f(x_c);
        const float dx = d_c * xv;
        float y = 0.f;
        #pragma unroll
        for (int k = 0; k < 4; k++) {
            float4 Bv = *(const float4*)&sBC[t][k*4];
            float4 Cv = *(const float4*)&sBC[t][16 + k*4];
            float bb[4] = { Bv.x, Bv.y, Bv.z, Bv.w };
            float cc[4] = { Cv.x, Cv.y, Cv.z, Cv.w };
            #pragma unroll
            for (int j = 0; j < 4; j++) {
                const int n = k*4 + j;
                const float dA = fexp2(d_c * en[n]);
                s[n] = fmaf(dA, s[n], dx * bb[j]);
                y = fmaf(cc[j], s[n], y);
            }
        }
        op[(size_t)t * 1024] = xr_c + y + Dv * xv;
        d_c = d_n; x_c = x_n; xr_c = xr_n;
    }
}

extern "C" void kernel_launch(void* const* d_in, const int* in_sizes, int n_in,
                              void* d_out, int out_size, void* d_ws, size_t ws_size,
                              hipStream_t stream)
{
    const float* x    = (const float*)d_in[0];
    const float* ln1g = (const float*)d_in[1];
    const float* ln1b = (const float*)d_in[2];
    const float* Wd   = (const float*)d_in[3];
    const float* bd   = (const float*)d_in[4];
    const float* Wbc  = (const float*)d_in[5];
    const float* bbc  = (const float*)d_in[6];
    const float* Alog = (const float*)d_in[7];
    const float* Dp   = (const float*)d_in[8];
    const float* ln2g = (const float*)d_in[9];
    const float* ln2b = (const float*)d_in[10];
    const float* W1   = (const float*)d_in[11];
    const float* b1   = (const float*)d_in[12];
    const float* W2   = (const float*)d_in[13];
    const float* b2   = (const float*)d_in[14];
    float* out = (float*)d_out;

    char* ws = (char*)d_ws;
    const size_t MB = 1024 * 1024;
    float*  deltaW = (float*)(ws + 0);            // 16 MiB (4096x1024 f32)
    float*  ssmW   = (float*)(ws + 16 * MB);      // 16 MiB (4096x1024 f32)
    USHORT* xnW    = (USHORT*)(ws + 32 * MB);     //  8 MiB (4096x1024 bf16)
    USHORT* nrmW   = (USHORT*)(ws + 40 * MB);     //  8 MiB (4096x1024 bf16)
    USHORT* hffW   = (USHORT*)(ws + 48 * MB);     // 32 MiB (4096x4096 bf16)
    float*  bcW    = (float*)(ws + 80 * MB);      // 512 KiB (4096x32 f32)
    USHORT* WdB    = (USHORT*)(ws + 81 * MB);     //  2 MiB (1024x1024 bf16)
    USHORT* W1B    = (USHORT*)(ws + 83 * MB);     //  8 MiB (4096x1024 bf16)
    USHORT* W2B    = (USHORT*)(ws + 91 * MB);     //  8 MiB (1024x4096 bf16)
    // scan scratch aliases hffW (dead until step 6): 3 x 8 MiB
    float*  sEndW  = (float*)(ws + 48 * MB);
    float*  PtotW  = (float*)(ws + 56 * MB);
    float*  sInW   = (float*)(ws + 64 * MB);
    // FFN2 split-K partials alias deltaW (splits 0,1) and xnW/nrmW (splits 2,3)
    // — both dead once scan_pass2 has run (FFN2 runs after FFN1).
    USHORT* ffn2p01 = (USHORT*)(ws + 0);          // 16 MiB: 2 x 4096x1024 bf16
    USHORT* ffn2p23 = (USHORT*)(ws + 32 * MB);    // 16 MiB: 2 x 4096x1024 bf16

    // 0. convert weights f32 -> bf16
    f2b_kernel<<<1024, 256, 0, stream>>>(Wd, WdB, 1024 * 1024);
    f2b_kernel<<<4096, 256, 0, stream>>>(W1, W1B, 4096 * 1024);
    f2b_kernel<<<4096, 256, 0, stream>>>(W2, W2B, 1024 * 4096);
    // 1. xn = LN1(x)                         (bf16)
    ln_kernel<<<4096, 256, 0, stream>>>(x, ln1g, ln1b, xnW);
    // 2. delta = softplus(xn @ Wd^T + bd)    (f32)
    gemm_bt<0><<<dim3(8, 32), 256, 0, stream>>>(xnW, WdB, bd, deltaW, nullptr, 4096, 1024, 1024, 1024, 1024);
    // 3. bc = xn @ Wbc^T + bbc               (f32)
    bc_kernel<<<4096, 256, 0, stream>>>(xnW, Wbc, bbc, bcW);
    // 4. ssm_out = x + scan(...) + D*xn      (f32), chunked parallel scan
    scan_pass1<<<dim3(4, 2, SCAN_P), 256, 0, stream>>>(xnW, deltaW, bcW, Alog, sEndW, PtotW);
    scan_mid<<<128, 256, 0, stream>>>(sEndW, PtotW, sInW);
    scan_pass2<<<dim3(4, 2, SCAN_P), 256, 0, stream>>>(x, xnW, deltaW, bcW, Alog, Dp, sInW, ssmW);
    // 5. normed = LN2(ssm_out)               (bf16)
    ln_kernel<<<4096, 256, 0, stream>>>(ssmW, ln2g, ln2b, nrmW);
    // 6. hff = gelu(normed @ W1^T + b1)      (bf16)
    gemm_bt<1><<<dim3(32, 32), 256, 0, stream>>>(nrmW, W1B, b1, hffW, nullptr, 4096, 4096, 1024, 1024, 1024);
    // 7a. FFN2 split-K=4 partial GEMMs       (bf16 partials, grid.z = split)
    gemm_bt<3><<<dim3(8, 32, 4), 256, 0, stream>>>(hffW, W2B, nullptr, ffn2p01, ffn2p23, 4096, 1024, 1024, 4096, 4096);
    // 7b. out = sum(partials) + b2 + ssm_out (f32)
    ffn2_reduce<<<4096, 256, 0, stream>>>(ffn2p01, ffn2p23, b2, ssmW, out);

    (void)in_sizes; (void)n_in; (void)out_size; (void)ws_size;
}

// Round 6
// 409.244 us; speedup vs baseline: 2.0087x; 1.0894x over previous
//
#include <hip/hip_runtime.h>
#include <cstdint>
#include <cstddef>

typedef unsigned short USHORT;
typedef __bf16 bf16x8 __attribute__((ext_vector_type(8)));
typedef float f32x4 __attribute__((ext_vector_type(4)));

__device__ __forceinline__ float b2f(USHORT u) {
    union { unsigned int i; float f; } v; v.i = ((unsigned int)u) << 16; return v.f;
}
__device__ __forceinline__ USHORT f2bf(float f) {
    union { float f; unsigned int i; } v; v.f = f;
    unsigned int u = v.i;
    unsigned int r = (u + 0x7FFFu + ((u >> 16) & 1u)) >> 16;
    return (USHORT)r;
}
__device__ __forceinline__ float fexp2(float x) { return __builtin_amdgcn_exp2f(x); }

__device__ __forceinline__ void gload_lds16(const void* g, void* l) {
    __builtin_amdgcn_global_load_lds(
        (const __attribute__((address_space(1))) void*)(uintptr_t)g,
        (__attribute__((address_space(3))) void*)(uint32_t)(uintptr_t)l,
        16, 0, 0);
}

// ---------------- f32 -> bf16 conversion (weights), 4 elems/thread ----------
__global__ __launch_bounds__(256)
void f2b_kernel(const float* __restrict__ src, USHORT* __restrict__ dst, int n)
{
    int i = (blockIdx.x * 256 + threadIdx.x) * 4;
    if (i < n) {
        float4 v = *(const float4*)(src + i);
        ushort4 o;
        o.x = f2bf(v.x); o.y = f2bf(v.y); o.z = f2bf(v.z); o.w = f2bf(v.w);
        *(ushort4*)(dst + i) = o;
    }
}

// ---------------- LayerNorm: f32 in -> bf16 out. 1 block/token, 256 thr ----
__global__ __launch_bounds__(256)
void ln_kernel(const float* __restrict__ inp, const float* __restrict__ g,
               const float* __restrict__ bsh, USHORT* __restrict__ out)
{
    const int tid = threadIdx.x;
    const size_t row = blockIdx.x;
    float4 t = ((const float4*)inp)[row * 256 + tid];
    float v[4] = { t.x, t.y, t.z, t.w };
    float s = v[0] + v[1] + v[2] + v[3];
    float sq = v[0]*v[0] + v[1]*v[1] + v[2]*v[2] + v[3]*v[3];
    #pragma unroll
    for (int off = 32; off; off >>= 1) { s += __shfl_down(s, off); sq += __shfl_down(sq, off); }
    __shared__ float red[8];
    const int wv = tid >> 6;
    if ((tid & 63) == 0) { red[wv] = s; red[wv + 4] = sq; }
    __syncthreads();
    const float S  = red[0] + red[1] + red[2] + red[3];
    const float SQ = red[4] + red[5] + red[6] + red[7];
    const float mu = S * (1.0f / 1024.0f);
    const float var = SQ * (1.0f / 1024.0f) - mu * mu;
    const float rs = rsqrtf(var + 1e-5f);
    float4 gv = ((const float4*)g)[tid];
    float4 bv = ((const float4*)bsh)[tid];
    ushort4 o;
    o.x = f2bf((v[0] - mu) * rs * gv.x + bv.x);
    o.y = f2bf((v[1] - mu) * rs * gv.y + bv.y);
    o.z = f2bf((v[2] - mu) * rs * gv.z + bv.z);
    o.w = f2bf((v[3] - mu) * rs * gv.w + bv.w);
    ((ushort4*)out)[row * 256 + tid] = o;
}

// ---------------- GEMM: C(M,N) = A(M,K) @ B(N,K)^T, bf16 MFMA, fused epilogue
// EPI 0: softplus -> f32 out (native exp2/log2)
// EPI 1: gelu (tanh form, native exp2/rcp) -> bf16 out
// EPI 3: split-K partial (blockIdx.z selects K-slice), raw bf16 partial out
// Epilogue goes through LDS (stride 68 pad -> <=2-way bank alias = free) so
// global stores are coalesced 128-256B segments instead of 32B scatters.
template<int EPI>
__global__ __launch_bounds__(256)
void gemm_bt(const USHORT* __restrict__ A, const USHORT* __restrict__ B,
             const float* __restrict__ bias, void* __restrict__ outp,
             void* __restrict__ outp2, int M, int N, int K, int lda, int ldb)
{
    __shared__ __align__(16) unsigned char smem[17408];  // 16KB staging / 17KB epilogue
    USHORT* As = (USHORT*)smem;
    USHORT* Bs = (USHORT*)(smem + 8192);
    const int tid = threadIdx.x;
    const int lane = tid & 63;
    const int w = tid >> 6;
    const int wr = w >> 1, wc = w & 1;
    const int tm = blockIdx.y * 128;
    const int tn = blockIdx.x * 128;

    USHORT* po = nullptr;
    if constexpr (EPI == 3) {
        const int z = blockIdx.z;
        A += (size_t)z * K;             // K-slice offset within row (lda=full K)
        B += (size_t)z * K;
        po = ((z < 2) ? (USHORT*)outp : (USHORT*)outp2) + (size_t)(z & 1) * M * N;
    }

    f32x4 acc[4][4];
    #pragma unroll
    for (int i = 0; i < 4; i++)
        #pragma unroll
        for (int j = 0; j < 4; j++) acc[i][j] = (f32x4){0.f, 0.f, 0.f, 0.f};

    const int srow = tid >> 2;          // 0..63
    const int scol = (tid & 3) * 8;     // 0,8,16,24
    const USHORT* gA0 = A + (size_t)(tm + srow) * lda + scol;
    const USHORT* gA1 = A + (size_t)(tm + 64 + srow) * lda + scol;
    const USHORT* gB0 = B + (size_t)(tn + srow) * ldb + scol;
    const USHORT* gB1 = B + (size_t)(tn + 64 + srow) * ldb + scol;
    USHORT* lA0 = As + w * 512;          // wave-uniform LDS bases
    USHORT* lA1 = As + 2048 + w * 512;
    USHORT* lB0 = Bs + w * 512;
    USHORT* lB1 = Bs + 2048 + w * 512;

    const int fr = lane & 15;
    const int fko = (lane >> 4) * 8;
    const int quad = lane >> 4;

    for (int k0 = 0; k0 < K; k0 += 32) {
        gload_lds16(gA0 + k0, lA0);
        gload_lds16(gA1 + k0, lA1);
        gload_lds16(gB0 + k0, lB0);
        gload_lds16(gB1 + k0, lB1);
        __syncthreads();
        bf16x8 af[4], bfr[4];
        #pragma unroll
        for (int i = 0; i < 4; i++) {
            af[i]  = *(const bf16x8*)(As + (wr * 64 + i * 16 + fr) * 32 + fko);
            bfr[i] = *(const bf16x8*)(Bs + (wc * 64 + i * 16 + fr) * 32 + fko);
        }
        #pragma unroll
        for (int i = 0; i < 4; i++)
            #pragma unroll
            for (int j = 0; j < 4; j++)
                acc[i][j] = __builtin_amdgcn_mfma_f32_16x16x32_bf16(af[i], bfr[j], acc[i][j], 0, 0, 0);
        __syncthreads();
    }

    // ---- epilogue: per-wave 16x64 f32 slices through LDS, coalesced stores
    float* eW = (float*)(smem + (size_t)w * 4352);   // 16 rows x 68 f32
    const int rr = lane >> 5;            // 0..1 (row within pair)
    const int cc = lane & 31;            // 0..31 (col pair)
    const int gcolb = tn + wc * 64;
    float2 bvv;
    if constexpr (EPI == 3) { bvv.x = 0.f; bvv.y = 0.f; }
    else bvv = *(const float2*)&bias[gcolb + cc * 2];

    #pragma unroll
    for (int i = 0; i < 4; i++) {
        #pragma unroll
        for (int j = 0; j < 4; j++)
            #pragma unroll
            for (int r = 0; r < 4; r++)
                eW[(quad * 4 + r) * 68 + j * 16 + fr] = acc[i][j][r];
        __syncthreads();
        const int grow0 = tm + wr * 64 + i * 16;
        #pragma unroll
        for (int rp = 0; rp < 8; rp++) {
            const int row = rp * 2 + rr;
            const float2 v = *(const float2*)&eW[row * 68 + cc * 2];
            const size_t gidx = (size_t)(grow0 + row) * N + gcolb + cc * 2;
            if constexpr (EPI == 0) {
                const float z0 = v.x + bvv.x, z1 = v.y + bvv.y;
                float2 o;
                o.x = (z0 > 20.f) ? z0 : 0.69314718f * __log2f(1.f + fexp2(z0 * 1.44269504f));
                o.y = (z1 > 20.f) ? z1 : 0.69314718f * __log2f(1.f + fexp2(z1 * 1.44269504f));
                *(float2*)((float*)outp + gidx) = o;
            } else if constexpr (EPI == 1) {
                const float z0 = v.x + bvv.x, z1 = v.y + bvv.y;
                const float u0 = z0 * (0.7978845608f + 0.035677408f * z0 * z0);
                const float u1 = z1 * (0.7978845608f + 0.035677408f * z1 * z1);
                const float s0 = __builtin_amdgcn_rcpf(1.f + fexp2(2.885390082f * u0));
                const float s1 = __builtin_amdgcn_rcpf(1.f + fexp2(2.885390082f * u1));
                const float g0 = z0 * (1.f - s0), g1 = z1 * (1.f - s1);
                const uint32_t pk = (uint32_t)f2bf(g0) | ((uint32_t)f2bf(g1) << 16);
                *(uint32_t*)((USHORT*)outp + gidx) = pk;
            } else {
                const uint32_t pk = (uint32_t)f2bf(v.x) | ((uint32_t)f2bf(v.y) << 16);
                *(uint32_t*)(po + gidx) = pk;
            }
        }
        __syncthreads();
    }
}

// ---------------- FFN2 split-K reduce: out = sum(partials) + bias + extra ---
__global__ __launch_bounds__(256)
void ffn2_reduce(const USHORT* __restrict__ p01, const USHORT* __restrict__ p23,
                 const float* __restrict__ bias, const float* __restrict__ extra,
                 float* __restrict__ out)
{
    const size_t PS = (size_t)4096 * 1024;      // one partial, elems
    const size_t i = ((size_t)blockIdx.x * 256 + threadIdx.x) * 4;
    ushort4 a = *(const ushort4*)(p01 + i);
    ushort4 b = *(const ushort4*)(p01 + PS + i);
    ushort4 c = *(const ushort4*)(p23 + i);
    ushort4 d = *(const ushort4*)(p23 + PS + i);
    float4 bv = *(const float4*)(bias + (i & 1023));
    float4 ev = *(const float4*)(extra + i);
    float4 o;
    o.x = b2f(a.x) + b2f(b.x) + b2f(c.x) + b2f(d.x) + bv.x + ev.x;
    o.y = b2f(a.y) + b2f(b.y) + b2f(c.y) + b2f(d.y) + bv.y + ev.y;
    o.z = b2f(a.z) + b2f(b.z) + b2f(c.z) + b2f(d.z) + bv.z + ev.z;
    o.w = b2f(a.w) + b2f(b.w) + b2f(c.w) + b2f(d.w) + bv.w + ev.w;
    *(float4*)(out + i) = o;
}

// ---------------- bc = xn @ Wbc^T + bbc : (4096 x 32), 1 block per token ----
__global__ __launch_bounds__(256)
void bc_kernel(const USHORT* __restrict__ xn, const float* __restrict__ Wbc,
               const float* __restrict__ bbc, float* __restrict__ bc)
{
    const int tok = blockIdx.x;
    const int n = threadIdx.x & 31;
    const int kg = threadIdx.x >> 5;   // 0..7
    const USHORT* xrow = xn + (size_t)tok * 1024 + kg * 128;
    const float* wrow = Wbc + (size_t)n * 1024 + kg * 128;
    float acc = 0.f;
    #pragma unroll 8
    for (int k = 0; k < 128; k += 4) {
        ushort4 xv = *(const ushort4*)(xrow + k);
        float4 wv = *(const float4*)(wrow + k);
        acc += b2f(xv.x) * wv.x + b2f(xv.y) * wv.y
             + b2f(xv.z) * wv.z + b2f(xv.w) * wv.w;
    }
    __shared__ float part[8][32];
    part[kg][n] = acc;
    __syncthreads();
    if (threadIdx.x < 32) {
        float r = bbc[threadIdx.x];
        #pragma unroll
        for (int i = 0; i < 8; i++) r += part[i][threadIdx.x];
        bc[(size_t)tok * 32 + threadIdx.x] = r;
    }
}

// ---------------- selective scan v3: chunked parallel, lane=h, n in regs ----
#define SCAN_P 64
#define SCAN_T 32

__global__ __launch_bounds__(256)
void scan_pass1(const USHORT* __restrict__ xn, const float* __restrict__ delta,
                const float* __restrict__ bc, const float* __restrict__ Alog,
                float* __restrict__ sEnd, float* __restrict__ Ptot)
{
    const int tid = threadIdx.x;
    const int h = blockIdx.x * 256 + tid;
    const int b = blockIdx.y;
    const int p = blockIdx.z;
    const size_t tok0 = (size_t)b * 2048 + p * SCAN_T;

    __shared__ __align__(16) float sBC[SCAN_T][32];
    {
        int t = tid >> 3, q = (tid & 7) * 4;
        *(float4*)&sBC[t][q] = *(const float4*)(bc + (tok0 + t) * 32 + q);
    }

    float en[16], s[16], P[16];
    #pragma unroll
    for (int k = 0; k < 4; k++) {
        float4 a = *(const float4*)(Alog + h * 16 + k * 4);
        en[k*4+0] = -__expf(a.x) * 1.44269504f;
        en[k*4+1] = -__expf(a.y) * 1.44269504f;
        en[k*4+2] = -__expf(a.z) * 1.44269504f;
        en[k*4+3] = -__expf(a.w) * 1.44269504f;
    }
    #pragma unroll
    for (int n = 0; n < 16; n++) { s[n] = 0.f; P[n] = 1.f; }
    __syncthreads();

    const float* dp = delta + tok0 * 1024 + h;
    const USHORT* xp = xn + tok0 * 1024 + h;
    float d_c = dp[0];
    USHORT x_c = xp[0];
    for (int t = 0; t < SCAN_T; ++t) {
        const int tn = (t < SCAN_T - 1) ? t + 1 : t;
        float d_n = dp[(size_t)tn * 1024];
        USHORT x_n = xp[(size_t)tn * 1024];
        const float dx = d_c * b2f(x_c);
        #pragma unroll
        for (int k = 0; k < 4; k++) {
            float4 Bv = *(const float4*)&sBC[t][k*4];
            float bb[4] = { Bv.x, Bv.y, Bv.z, Bv.w };
            #pragma unroll
            for (int j = 0; j < 4; j++) {
                const int n = k*4 + j;
                const float dA = fexp2(d_c * en[n]);
                s[n] = fmaf(dA, s[n], dx * bb[j]);
                P[n] *= dA;
            }
        }
        d_c = d_n; x_c = x_n;
    }

    const size_t off = (size_t)p * 32768 + ((size_t)b * 1024 + h) * 16;
    #pragma unroll
    for (int k = 0; k < 4; k++) {
        *(float4*)(sEnd + off + k*4) = (float4){ s[k*4], s[k*4+1], s[k*4+2], s[k*4+3] };
        *(float4*)(Ptot + off + k*4) = (float4){ P[k*4], P[k*4+1], P[k*4+2], P[k*4+3] };
    }
}

__global__ __launch_bounds__(256)
void scan_mid(const float* __restrict__ sEnd, const float* __restrict__ Ptot,
              float* __restrict__ sIn)
{
    const int L = blockIdx.x * 256 + threadIdx.x;   // 0..32767 = (b*1024+h)*16+n
    float s = 0.f;
    #pragma unroll 8
    for (int p = 0; p < SCAN_P; ++p) {
        const size_t off = (size_t)p * 32768 + L;
        sIn[off] = s;
        s = fmaf(Ptot[off], s, sEnd[off]);
    }
}

__global__ __launch_bounds__(256)
void scan_pass2(const float* __restrict__ x, const USHORT* __restrict__ xn,
                const float* __restrict__ delta, const float* __restrict__ bc,
                const float* __restrict__ Alog, const float* __restrict__ Dp,
                const float* __restrict__ sIn, float* __restrict__ ssm)
{
    const int tid = threadIdx.x;
    const int h = blockIdx.x * 256 + tid;
    const int b = blockIdx.y;
    const int p = blockIdx.z;
    const size_t tok0 = (size_t)b * 2048 + p * SCAN_T;

    __shared__ __align__(16) float sBC[SCAN_T][32];
    {
        int t = tid >> 3, q = (tid & 7) * 4;
        *(float4*)&sBC[t][q] = *(const float4*)(bc + (tok0 + t) * 32 + q);
    }

    float en[16], s[16];
    #pragma unroll
    for (int k = 0; k < 4; k++) {
        float4 a = *(const float4*)(Alog + h * 16 + k * 4);
        en[k*4+0] = -__expf(a.x) * 1.44269504f;
        en[k*4+1] = -__expf(a.y) * 1.44269504f;
        en[k*4+2] = -__expf(a.z) * 1.44269504f;
        en[k*4+3] = -__expf(a.w) * 1.44269504f;
    }
    const size_t off = (size_t)p * 32768 + ((size_t)b * 1024 + h) * 16;
    #pragma unroll
    for (int k = 0; k < 4; k++) {
        float4 v = *(const float4*)(sIn + off + k*4);
        s[k*4] = v.x; s[k*4+1] = v.y; s[k*4+2] = v.z; s[k*4+3] = v.w;
    }
    const float Dv = Dp[h];
    __syncthreads();

    const float* dp = delta + tok0 * 1024 + h;
    const USHORT* xp = xn + tok0 * 1024 + h;
    const float* xrp = x + tok0 * 1024 + h;
    float* op = ssm + tok0 * 1024 + h;

    float d_c = dp[0];
    USHORT x_c = xp[0];
    float xr_c = xrp[0];
    for (int t = 0; t < SCAN_T; ++t) {
        const int tn = (t < SCAN_T - 1) ? t + 1 : t;
        float d_n = dp[(size_t)tn * 1024];
        USHORT x_n = xp[(size_t)tn * 1024];
        float xr_n = xrp[(size_t)tn * 1024];
        const float xv = b2f(x_c);
        const float dx = d_c * xv;
        float y = 0.f;
        #pragma unroll
        for (int k = 0; k < 4; k++) {
            float4 Bv = *(const float4*)&sBC[t][k*4];
            float4 Cv = *(const float4*)&sBC[t][16 + k*4];
            float bb[4] = { Bv.x, Bv.y, Bv.z, Bv.w };
            float cc[4] = { Cv.x, Cv.y, Cv.z, Cv.w };
            #pragma unroll
            for (int j = 0; j < 4; j++) {
                const int n = k*4 + j;
                const float dA = fexp2(d_c * en[n]);
                s[n] = fmaf(dA, s[n], dx * bb[j]);
                y = fmaf(cc[j], s[n], y);
            }
        }
        op[(size_t)t * 1024] = xr_c + y + Dv * xv;
        d_c = d_n; x_c = x_n; xr_c = xr_n;
    }
}

extern "C" void kernel_launch(void* const* d_in, const int* in_sizes, int n_in,
                              void* d_out, int out_size, void* d_ws, size_t ws_size,
                              hipStream_t stream)
{
    const float* x    = (const float*)d_in[0];
    const float* ln1g = (const float*)d_in[1];
    const float* ln1b = (const float*)d_in[2];
    const float* Wd   = (const float*)d_in[3];
    const float* bd   = (const float*)d_in[4];
    const float* Wbc  = (const float*)d_in[5];
    const float* bbc  = (const float*)d_in[6];
    const float* Alog = (const float*)d_in[7];
    const float* Dp   = (const float*)d_in[8];
    const float* ln2g = (const float*)d_in[9];
    const float* ln2b = (const float*)d_in[10];
    const float* W1   = (const float*)d_in[11];
    const float* b1   = (const float*)d_in[12];
    const float* W2   = (const float*)d_in[13];
    const float* b2   = (const float*)d_in[14];
    float* out = (float*)d_out;

    char* ws = (char*)d_ws;
    const size_t MB = 1024 * 1024;
    float*  deltaW = (float*)(ws + 0);            // 16 MiB (4096x1024 f32)
    float*  ssmW   = (float*)(ws + 16 * MB);      // 16 MiB (4096x1024 f32)
    USHORT* xnW    = (USHORT*)(ws + 32 * MB);     //  8 MiB (4096x1024 bf16)
    USHORT* nrmW   = (USHORT*)(ws + 40 * MB);     //  8 MiB (4096x1024 bf16)
    USHORT* hffW   = (USHORT*)(ws + 48 * MB);     // 32 MiB (4096x4096 bf16)
    float*  bcW    = (float*)(ws + 80 * MB);      // 512 KiB (4096x32 f32)
    USHORT* WdB    = (USHORT*)(ws + 81 * MB);     //  2 MiB (1024x1024 bf16)
    USHORT* W1B    = (USHORT*)(ws + 83 * MB);     //  8 MiB (4096x1024 bf16)
    USHORT* W2B    = (USHORT*)(ws + 91 * MB);     //  8 MiB (1024x4096 bf16)
    // scan scratch aliases hffW (dead until step 6): 3 x 8 MiB
    float*  sEndW  = (float*)(ws + 48 * MB);
    float*  PtotW  = (float*)(ws + 56 * MB);
    float*  sInW   = (float*)(ws + 64 * MB);
    // FFN2 split-K partials alias deltaW (splits 0,1) and xnW/nrmW (splits 2,3)
    USHORT* ffn2p01 = (USHORT*)(ws + 0);          // 16 MiB: 2 x 4096x1024 bf16
    USHORT* ffn2p23 = (USHORT*)(ws + 32 * MB);    // 16 MiB: 2 x 4096x1024 bf16

    // 0. convert weights f32 -> bf16
    f2b_kernel<<<1024, 256, 0, stream>>>(Wd, WdB, 1024 * 1024);
    f2b_kernel<<<4096, 256, 0, stream>>>(W1, W1B, 4096 * 1024);
    f2b_kernel<<<4096, 256, 0, stream>>>(W2, W2B, 1024 * 4096);
    // 1. xn = LN1(x)                         (bf16)
    ln_kernel<<<4096, 256, 0, stream>>>(x, ln1g, ln1b, xnW);
    // 2. delta = softplus(xn @ Wd^T + bd)    (f32)
    gemm_bt<0><<<dim3(8, 32), 256, 0, stream>>>(xnW, WdB, bd, deltaW, nullptr, 4096, 1024, 1024, 1024, 1024);
    // 3. bc = xn @ Wbc^T + bbc               (f32)
    bc_kernel<<<4096, 256, 0, stream>>>(xnW, Wbc, bbc, bcW);
    // 4. ssm_out = x + scan(...) + D*xn      (f32), chunked parallel scan
    scan_pass1<<<dim3(4, 2, SCAN_P), 256, 0, stream>>>(xnW, deltaW, bcW, Alog, sEndW, PtotW);
    scan_mid<<<128, 256, 0, stream>>>(sEndW, PtotW, sInW);
    scan_pass2<<<dim3(4, 2, SCAN_P), 256, 0, stream>>>(x, xnW, deltaW, bcW, Alog, Dp, sInW, ssmW);
    // 5. normed = LN2(ssm_out)               (bf16)
    ln_kernel<<<4096, 256, 0, stream>>>(ssmW, ln2g, ln2b, nrmW);
    // 6. hff = gelu(normed @ W1^T + b1)      (bf16)
    gemm_bt<1><<<dim3(32, 32), 256, 0, stream>>>(nrmW, W1B, b1, hffW, nullptr, 4096, 4096, 1024, 1024, 1024);
    // 7a. FFN2 split-K=4 partial GEMMs       (bf16 partials, grid.z = split)
    gemm_bt<3><<<dim3(8, 32, 4), 256, 0, stream>>>(hffW, W2B, nullptr, ffn2p01, ffn2p23, 4096, 1024, 1024, 4096, 4096);
    // 7b. out = sum(partials) + b2 + ssm_out (f32)
    ffn2_reduce<<<4096, 256, 0, stream>>>(ffn2p01, ffn2p23, b2, ssmW, out);

    (void)in_sizes; (void)n_in; (void)out_size; (void)ws_size;
}

// Round 7
// 398.482 us; speedup vs baseline: 2.0630x; 1.0270x over previous
//
#include <hip/hip_runtime.h>
#include <cstdint>
#include <cstddef>

typedef unsigned short USHORT;
typedef __bf16 bf16x8 __attribute__((ext_vector_type(8)));
typedef float f32x4 __attribute__((ext_vector_type(4)));

__device__ __forceinline__ float b2f(USHORT u) {
    union { unsigned int i; float f; } v; v.i = ((unsigned int)u) << 16; return v.f;
}
__device__ __forceinline__ USHORT f2bf(float f) {
    union { float f; unsigned int i; } v; v.f = f;
    unsigned int u = v.i;
    unsigned int r = (u + 0x7FFFu + ((u >> 16) & 1u)) >> 16;
    return (USHORT)r;
}
__device__ __forceinline__ float fexp2(float x) { return __builtin_amdgcn_exp2f(x); }

__device__ __forceinline__ void gload_lds16(const void* g, void* l) {
    __builtin_amdgcn_global_load_lds(
        (const __attribute__((address_space(1))) void*)(uintptr_t)g,
        (__attribute__((address_space(3))) void*)(uint32_t)(uintptr_t)l,
        16, 0, 0);
}

// ---------------- f32 -> bf16 conversion (weights), 4 elems/thread ----------
__global__ __launch_bounds__(256)
void f2b_kernel(const float* __restrict__ src, USHORT* __restrict__ dst, int n)
{
    int i = (blockIdx.x * 256 + threadIdx.x) * 4;
    if (i < n) {
        float4 v = *(const float4*)(src + i);
        ushort4 o;
        o.x = f2bf(v.x); o.y = f2bf(v.y); o.z = f2bf(v.z); o.w = f2bf(v.w);
        *(ushort4*)(dst + i) = o;
    }
}

// ---------------- LayerNorm: f32 in -> bf16 out. 1 block/token, 256 thr ----
__global__ __launch_bounds__(256)
void ln_kernel(const float* __restrict__ inp, const float* __restrict__ g,
               const float* __restrict__ bsh, USHORT* __restrict__ out)
{
    const int tid = threadIdx.x;
    const size_t row = blockIdx.x;
    float4 t = ((const float4*)inp)[row * 256 + tid];
    float v[4] = { t.x, t.y, t.z, t.w };
    float s = v[0] + v[1] + v[2] + v[3];
    float sq = v[0]*v[0] + v[1]*v[1] + v[2]*v[2] + v[3]*v[3];
    #pragma unroll
    for (int off = 32; off; off >>= 1) { s += __shfl_down(s, off); sq += __shfl_down(sq, off); }
    __shared__ float red[8];
    const int wv = tid >> 6;
    if ((tid & 63) == 0) { red[wv] = s; red[wv + 4] = sq; }
    __syncthreads();
    const float S  = red[0] + red[1] + red[2] + red[3];
    const float SQ = red[4] + red[5] + red[6] + red[7];
    const float mu = S * (1.0f / 1024.0f);
    const float var = SQ * (1.0f / 1024.0f) - mu * mu;
    const float rs = rsqrtf(var + 1e-5f);
    float4 gv = ((const float4*)g)[tid];
    float4 bv = ((const float4*)bsh)[tid];
    ushort4 o;
    o.x = f2bf((v[0] - mu) * rs * gv.x + bv.x);
    o.y = f2bf((v[1] - mu) * rs * gv.y + bv.y);
    o.z = f2bf((v[2] - mu) * rs * gv.z + bv.z);
    o.w = f2bf((v[3] - mu) * rs * gv.w + bv.w);
    ((ushort4*)out)[row * 256 + tid] = o;
}

// ---------------- GEMM: C(M,N) = A(M,K) @ B(N,K)^T, bf16 MFMA, fused epilogue
// EPI 1: gelu (tanh form, native exp2/rcp) -> bf16 out
// EPI 3: split-K partial (blockIdx.z selects K-slice), raw bf16 partial out
//        partial z lives at (z<2 ? outp : outp2) + (z&1)*M*N
// GROUP_M=8 pid swizzle: 8 consecutive pids share one n-column -> L2 reuse.
// Epilogue via LDS (stride 68) -> coalesced global stores.
template<int EPI>
__global__ __launch_bounds__(256)
void gemm_bt(const USHORT* __restrict__ A, const USHORT* __restrict__ B,
             const float* __restrict__ bias, void* __restrict__ outp,
             void* __restrict__ outp2, int M, int N, int K, int lda, int ldb)
{
    __shared__ __align__(16) unsigned char smem[17408];  // 16KB staging / 17KB epilogue
    USHORT* As = (USHORT*)smem;
    USHORT* Bs = (USHORT*)(smem + 8192);
    const int tid = threadIdx.x;
    const int lane = tid & 63;
    const int w = tid >> 6;
    const int wr = w >> 1, wc = w & 1;

    // GROUP_M=8 swizzle over the (gridDim.x x gridDim.y) tile grid
    const int nx = gridDim.x, ny = gridDim.y;
    const int pid = blockIdx.y * nx + blockIdx.x;
    const int npg = 8 * nx;
    const int gid = pid / npg;
    const int first = gid * 8;
    const int rem = ny - first;
    const int gsz = (rem < 8) ? rem : 8;
    const int py = first + (pid % npg) % gsz;
    const int px = (pid % npg) / gsz;
    const int tm = py * 128;
    const int tn = px * 128;

    USHORT* po = nullptr;
    if constexpr (EPI == 3) {
        const int z = blockIdx.z;
        A += (size_t)z * K;             // K-slice offset within row (lda=full K)
        B += (size_t)z * K;
        po = ((z < 2) ? (USHORT*)outp : (USHORT*)outp2) + (size_t)(z & 1) * M * N;
    }

    f32x4 acc[4][4];
    #pragma unroll
    for (int i = 0; i < 4; i++)
        #pragma unroll
        for (int j = 0; j < 4; j++) acc[i][j] = (f32x4){0.f, 0.f, 0.f, 0.f};

    const int srow = tid >> 2;          // 0..63
    const int scol = (tid & 3) * 8;     // 0,8,16,24
    const USHORT* gA0 = A + (size_t)(tm + srow) * lda + scol;
    const USHORT* gA1 = A + (size_t)(tm + 64 + srow) * lda + scol;
    const USHORT* gB0 = B + (size_t)(tn + srow) * ldb + scol;
    const USHORT* gB1 = B + (size_t)(tn + 64 + srow) * ldb + scol;
    USHORT* lA0 = As + w * 512;          // wave-uniform LDS bases
    USHORT* lA1 = As + 2048 + w * 512;
    USHORT* lB0 = Bs + w * 512;
    USHORT* lB1 = Bs + 2048 + w * 512;

    const int fr = lane & 15;
    const int fko = (lane >> 4) * 8;
    const int quad = lane >> 4;

    for (int k0 = 0; k0 < K; k0 += 32) {
        gload_lds16(gA0 + k0, lA0);
        gload_lds16(gA1 + k0, lA1);
        gload_lds16(gB0 + k0, lB0);
        gload_lds16(gB1 + k0, lB1);
        __syncthreads();
        bf16x8 af[4], bfr[4];
        #pragma unroll
        for (int i = 0; i < 4; i++) {
            af[i]  = *(const bf16x8*)(As + (wr * 64 + i * 16 + fr) * 32 + fko);
            bfr[i] = *(const bf16x8*)(Bs + (wc * 64 + i * 16 + fr) * 32 + fko);
        }
        #pragma unroll
        for (int i = 0; i < 4; i++)
            #pragma unroll
            for (int j = 0; j < 4; j++)
                acc[i][j] = __builtin_amdgcn_mfma_f32_16x16x32_bf16(af[i], bfr[j], acc[i][j], 0, 0, 0);
        __syncthreads();
    }

    // ---- epilogue: per-wave 16x64 f32 slices through LDS, coalesced stores
    float* eW = (float*)(smem + (size_t)w * 4352);   // 16 rows x 68 f32
    const int rr = lane >> 5;            // 0..1 (row within pair)
    const int cc = lane & 31;            // 0..31 (col pair)
    const int gcolb = tn + wc * 64;
    float2 bvv;
    if constexpr (EPI == 3) { bvv.x = 0.f; bvv.y = 0.f; }
    else bvv = *(const float2*)&bias[gcolb + cc * 2];

    #pragma unroll
    for (int i = 0; i < 4; i++) {
        #pragma unroll
        for (int j = 0; j < 4; j++)
            #pragma unroll
            for (int r = 0; r < 4; r++)
                eW[(quad * 4 + r) * 68 + j * 16 + fr] = acc[i][j][r];
        __syncthreads();
        const int grow0 = tm + wr * 64 + i * 16;
        #pragma unroll
        for (int rp = 0; rp < 8; rp++) {
            const int row = rp * 2 + rr;
            const float2 v = *(const float2*)&eW[row * 68 + cc * 2];
            const size_t gidx = (size_t)(grow0 + row) * N + gcolb + cc * 2;
            if constexpr (EPI == 1) {
                const float z0 = v.x + bvv.x, z1 = v.y + bvv.y;
                const float u0 = z0 * (0.7978845608f + 0.035677408f * z0 * z0);
                const float u1 = z1 * (0.7978845608f + 0.035677408f * z1 * z1);
                const float s0 = __builtin_amdgcn_rcpf(1.f + fexp2(2.885390082f * u0));
                const float s1 = __builtin_amdgcn_rcpf(1.f + fexp2(2.885390082f * u1));
                const float g0 = z0 * (1.f - s0), g1 = z1 * (1.f - s1);
                const uint32_t pk = (uint32_t)f2bf(g0) | ((uint32_t)f2bf(g1) << 16);
                *(uint32_t*)((USHORT*)outp + gidx) = pk;
            } else {
                const uint32_t pk = (uint32_t)f2bf(v.x) | ((uint32_t)f2bf(v.y) << 16);
                *(uint32_t*)(po + gidx) = pk;
            }
        }
        __syncthreads();
    }
}

// ---------------- delta split-K reduce: delta = softplus(p0+p1+bias), f32 ---
__global__ __launch_bounds__(256)
void delta_reduce(const USHORT* __restrict__ p, const float* __restrict__ bias,
                  float* __restrict__ out)
{
    const size_t PS = (size_t)4096 * 1024;
    const size_t i = ((size_t)blockIdx.x * 256 + threadIdx.x) * 4;
    ushort4 a = *(const ushort4*)(p + i);
    ushort4 b = *(const ushort4*)(p + PS + i);
    float4 bv = *(const float4*)(bias + (i & 1023));
    float z[4] = { b2f(a.x) + b2f(b.x) + bv.x, b2f(a.y) + b2f(b.y) + bv.y,
                   b2f(a.z) + b2f(b.z) + bv.z, b2f(a.w) + b2f(b.w) + bv.w };
    float4 o;
    o.x = (z[0] > 20.f) ? z[0] : 0.69314718f * __log2f(1.f + fexp2(z[0] * 1.44269504f));
    o.y = (z[1] > 20.f) ? z[1] : 0.69314718f * __log2f(1.f + fexp2(z[1] * 1.44269504f));
    o.z = (z[2] > 20.f) ? z[2] : 0.69314718f * __log2f(1.f + fexp2(z[2] * 1.44269504f));
    o.w = (z[3] > 20.f) ? z[3] : 0.69314718f * __log2f(1.f + fexp2(z[3] * 1.44269504f));
    *(float4*)(out + i) = o;
}

// ---------------- FFN2 split-K reduce: out = sum(partials) + bias + extra ---
__global__ __launch_bounds__(256)
void ffn2_reduce(const USHORT* __restrict__ p01, const USHORT* __restrict__ p23,
                 const float* __restrict__ bias, const float* __restrict__ extra,
                 float* __restrict__ out)
{
    const size_t PS = (size_t)4096 * 1024;      // one partial, elems
    const size_t i = ((size_t)blockIdx.x * 256 + threadIdx.x) * 4;
    ushort4 a = *(const ushort4*)(p01 + i);
    ushort4 b = *(const ushort4*)(p01 + PS + i);
    ushort4 c = *(const ushort4*)(p23 + i);
    ushort4 d = *(const ushort4*)(p23 + PS + i);
    float4 bv = *(const float4*)(bias + (i & 1023));
    float4 ev = *(const float4*)(extra + i);
    float4 o;
    o.x = b2f(a.x) + b2f(b.x) + b2f(c.x) + b2f(d.x) + bv.x + ev.x;
    o.y = b2f(a.y) + b2f(b.y) + b2f(c.y) + b2f(d.y) + bv.y + ev.y;
    o.z = b2f(a.z) + b2f(b.z) + b2f(c.z) + b2f(d.z) + bv.z + ev.z;
    o.w = b2f(a.w) + b2f(b.w) + b2f(c.w) + b2f(d.w) + bv.w + ev.w;
    *(float4*)(out + i) = o;
}

// ---------------- bc = xn @ Wbc^T + bbc : (4096 x 32), 1 block per token ----
__global__ __launch_bounds__(256)
void bc_kernel(const USHORT* __restrict__ xn, const float* __restrict__ Wbc,
               const float* __restrict__ bbc, float* __restrict__ bc)
{
    const int tok = blockIdx.x;
    const int n = threadIdx.x & 31;
    const int kg = threadIdx.x >> 5;   // 0..7
    const USHORT* xrow = xn + (size_t)tok * 1024 + kg * 128;
    const float* wrow = Wbc + (size_t)n * 1024 + kg * 128;
    float acc = 0.f;
    #pragma unroll 8
    for (int k = 0; k < 128; k += 4) {
        ushort4 xv = *(const ushort4*)(xrow + k);
        float4 wv = *(const float4*)(wrow + k);
        acc += b2f(xv.x) * wv.x + b2f(xv.y) * wv.y
             + b2f(xv.z) * wv.z + b2f(xv.w) * wv.w;
    }
    __shared__ float part[8][32];
    part[kg][n] = acc;
    __syncthreads();
    if (threadIdx.x < 32) {
        float r = bbc[threadIdx.x];
        #pragma unroll
        for (int i = 0; i < 8; i++) r += part[i][threadIdx.x];
        bc[(size_t)tok * 32 + threadIdx.x] = r;
    }
}

// ---------------- selective scan v3: chunked parallel, lane=h, n in regs ----
#define SCAN_P 64
#define SCAN_T 32

__global__ __launch_bounds__(256)
void scan_pass1(const USHORT* __restrict__ xn, const float* __restrict__ delta,
                const float* __restrict__ bc, const float* __restrict__ Alog,
                float* __restrict__ sEnd, float* __restrict__ Ptot)
{
    const int tid = threadIdx.x;
    const int h = blockIdx.x * 256 + tid;
    const int b = blockIdx.y;
    const int p = blockIdx.z;
    const size_t tok0 = (size_t)b * 2048 + p * SCAN_T;

    __shared__ __align__(16) float sBC[SCAN_T][32];
    {
        int t = tid >> 3, q = (tid & 7) * 4;
        *(float4*)&sBC[t][q] = *(const float4*)(bc + (tok0 + t) * 32 + q);
    }

    float en[16], s[16], P[16];
    #pragma unroll
    for (int k = 0; k < 4; k++) {
        float4 a = *(const float4*)(Alog + h * 16 + k * 4);
        en[k*4+0] = -__expf(a.x) * 1.44269504f;
        en[k*4+1] = -__expf(a.y) * 1.44269504f;
        en[k*4+2] = -__expf(a.z) * 1.44269504f;
        en[k*4+3] = -__expf(a.w) * 1.44269504f;
    }
    #pragma unroll
    for (int n = 0; n < 16; n++) { s[n] = 0.f; P[n] = 1.f; }
    __syncthreads();

    const float* dp = delta + tok0 * 1024 + h;
    const USHORT* xp = xn + tok0 * 1024 + h;
    float d_c = dp[0];
    USHORT x_c = xp[0];
    for (int t = 0; t < SCAN_T; ++t) {
        const int tn = (t < SCAN_T - 1) ? t + 1 : t;
        float d_n = dp[(size_t)tn * 1024];
        USHORT x_n = xp[(size_t)tn * 1024];
        const float dx = d_c * b2f(x_c);
        #pragma unroll
        for (int k = 0; k < 4; k++) {
            float4 Bv = *(const float4*)&sBC[t][k*4];
            float bb[4] = { Bv.x, Bv.y, Bv.z, Bv.w };
            #pragma unroll
            for (int j = 0; j < 4; j++) {
                const int n = k*4 + j;
                const float dA = fexp2(d_c * en[n]);
                s[n] = fmaf(dA, s[n], dx * bb[j]);
                P[n] *= dA;
            }
        }
        d_c = d_n; x_c = x_n;
    }

    const size_t off = (size_t)p * 32768 + ((size_t)b * 1024 + h) * 16;
    #pragma unroll
    for (int k = 0; k < 4; k++) {
        *(float4*)(sEnd + off + k*4) = (float4){ s[k*4], s[k*4+1], s[k*4+2], s[k*4+3] };
        *(float4*)(Ptot + off + k*4) = (float4){ P[k*4], P[k*4+1], P[k*4+2], P[k*4+3] };
    }
}

__global__ __launch_bounds__(256)
void scan_mid(const float* __restrict__ sEnd, const float* __restrict__ Ptot,
              float* __restrict__ sIn)
{
    const int L = blockIdx.x * 256 + threadIdx.x;   // 0..32767 = (b*1024+h)*16+n
    float s = 0.f;
    #pragma unroll 8
    for (int p = 0; p < SCAN_P; ++p) {
        const size_t off = (size_t)p * 32768 + L;
        sIn[off] = s;
        s = fmaf(Ptot[off], s, sEnd[off]);
    }
}

__global__ __launch_bounds__(256)
void scan_pass2(const float* __restrict__ x, const USHORT* __restrict__ xn,
                const float* __restrict__ delta, const float* __restrict__ bc,
                const float* __restrict__ Alog, const float* __restrict__ Dp,
                const float* __restrict__ sIn, float* __restrict__ ssm)
{
    const int tid = threadIdx.x;
    const int h = blockIdx.x * 256 + tid;
    const int b = blockIdx.y;
    const int p = blockIdx.z;
    const size_t tok0 = (size_t)b * 2048 + p * SCAN_T;

    __shared__ __align__(16) float sBC[SCAN_T][32];
    {
        int t = tid >> 3, q = (tid & 7) * 4;
        *(float4*)&sBC[t][q] = *(const float4*)(bc + (tok0 + t) * 32 + q);
    }

    float en[16], s[16];
    #pragma unroll
    for (int k = 0; k < 4; k++) {
        float4 a = *(const float4*)(Alog + h * 16 + k * 4);
        en[k*4+0] = -__expf(a.x) * 1.44269504f;
        en[k*4+1] = -__expf(a.y) * 1.44269504f;
        en[k*4+2] = -__expf(a.z) * 1.44269504f;
        en[k*4+3] = -__expf(a.w) * 1.44269504f;
    }
    const size_t off = (size_t)p * 32768 + ((size_t)b * 1024 + h) * 16;
    #pragma unroll
    for (int k = 0; k < 4; k++) {
        float4 v = *(const float4*)(sIn + off + k*4);
        s[k*4] = v.x; s[k*4+1] = v.y; s[k*4+2] = v.z; s[k*4+3] = v.w;
    }
    const float Dv = Dp[h];
    __syncthreads();

    const float* dp = delta + tok0 * 1024 + h;
    const USHORT* xp = xn + tok0 * 1024 + h;
    const float* xrp = x + tok0 * 1024 + h;
    float* op = ssm + tok0 * 1024 + h;

    float d_c = dp[0];
    USHORT x_c = xp[0];
    float xr_c = xrp[0];
    for (int t = 0; t < SCAN_T; ++t) {
        const int tn = (t < SCAN_T - 1) ? t + 1 : t;
        float d_n = dp[(size_t)tn * 1024];
        USHORT x_n = xp[(size_t)tn * 1024];
        float xr_n = xrp[(size_t)tn * 1024];
        const float xv = b2f(x_c);
        const float dx = d_c * xv;
        float y = 0.f;
        #pragma unroll
        for (int k = 0; k < 4; k++) {
            float4 Bv = *(const float4*)&sBC[t][k*4];
            float4 Cv = *(const float4*)&sBC[t][16 + k*4];
            float bb[4] = { Bv.x, Bv.y, Bv.z, Bv.w };
            float cc[4] = { Cv.x, Cv.y, Cv.z, Cv.w };
            #pragma unroll
            for (int j = 0; j < 4; j++) {
                const int n = k*4 + j;
                const float dA = fexp2(d_c * en[n]);
                s[n] = fmaf(dA, s[n], dx * bb[j]);
                y = fmaf(cc[j], s[n], y);
            }
        }
        op[(size_t)t * 1024] = xr_c + y + Dv * xv;
        d_c = d_n; x_c = x_n; xr_c = xr_n;
    }
}

extern "C" void kernel_launch(void* const* d_in, const int* in_sizes, int n_in,
                              void* d_out, int out_size, void* d_ws, size_t ws_size,
                              hipStream_t stream)
{
    const float* x    = (const float*)d_in[0];
    const float* ln1g = (const float*)d_in[1];
    const float* ln1b = (const float*)d_in[2];
    const float* Wd   = (const float*)d_in[3];
    const float* bd   = (const float*)d_in[4];
    const float* Wbc  = (const float*)d_in[5];
    const float* bbc  = (const float*)d_in[6];
    const float* Alog = (const float*)d_in[7];
    const float* Dp   = (const float*)d_in[8];
    const float* ln2g = (const float*)d_in[9];
    const float* ln2b = (const float*)d_in[10];
    const float* W1   = (const float*)d_in[11];
    const float* b1   = (const float*)d_in[12];
    const float* W2   = (const float*)d_in[13];
    const float* b2   = (const float*)d_in[14];
    float* out = (float*)d_out;

    char* ws = (char*)d_ws;
    const size_t MB = 1024 * 1024;
    float*  deltaW = (float*)(ws + 0);            // 16 MiB (4096x1024 f32)
    float*  ssmW   = (float*)(ws + 16 * MB);      // 16 MiB (4096x1024 f32)
    USHORT* xnW    = (USHORT*)(ws + 32 * MB);     //  8 MiB (4096x1024 bf16)
    USHORT* nrmW   = (USHORT*)(ws + 40 * MB);     //  8 MiB (4096x1024 bf16)
    USHORT* hffW   = (USHORT*)(ws + 48 * MB);     // 32 MiB (4096x4096 bf16)
    float*  bcW    = (float*)(ws + 80 * MB);      // 512 KiB (4096x32 f32)
    USHORT* WdB    = (USHORT*)(ws + 81 * MB);     //  2 MiB (1024x1024 bf16)
    USHORT* W1B    = (USHORT*)(ws + 83 * MB);     //  8 MiB (4096x1024 bf16)
    USHORT* W2B    = (USHORT*)(ws + 91 * MB);     //  8 MiB (1024x4096 bf16)
    // delta split-K partials alias hffW (dead until step 6): 2 x 8 MiB
    USHORT* dpart  = (USHORT*)(ws + 48 * MB);
    // scan scratch aliases hffW too (delta reduce finishes first): 3 x 8 MiB
    float*  sEndW  = (float*)(ws + 48 * MB);
    float*  PtotW  = (float*)(ws + 56 * MB);
    float*  sInW   = (float*)(ws + 64 * MB);
    // FFN2 split-K partials alias deltaW (splits 0,1) and xnW/nrmW (splits 2,3)
    USHORT* ffn2p01 = (USHORT*)(ws + 0);          // 16 MiB: 2 x 4096x1024 bf16
    USHORT* ffn2p23 = (USHORT*)(ws + 32 * MB);    // 16 MiB: 2 x 4096x1024 bf16

    // 0. convert weights f32 -> bf16
    f2b_kernel<<<1024, 256, 0, stream>>>(Wd, WdB, 1024 * 1024);
    f2b_kernel<<<4096, 256, 0, stream>>>(W1, W1B, 4096 * 1024);
    f2b_kernel<<<4096, 256, 0, stream>>>(W2, W2B, 1024 * 4096);
    // 1. xn = LN1(x)                         (bf16)
    ln_kernel<<<4096, 256, 0, stream>>>(x, ln1g, ln1b, xnW);
    // 2a. delta split-K=2 partial GEMMs      (bf16 partials)
    gemm_bt<3><<<dim3(8, 32, 2), 256, 0, stream>>>(xnW, WdB, nullptr, dpart, nullptr, 4096, 1024, 512, 1024, 1024);
    // 2b. delta = softplus(p0+p1+bd)         (f32)
    delta_reduce<<<4096, 256, 0, stream>>>(dpart, bd, deltaW);
    // 3. bc = xn @ Wbc^T + bbc               (f32)
    bc_kernel<<<4096, 256, 0, stream>>>(xnW, Wbc, bbc, bcW);
    // 4. ssm_out = x + scan(...) + D*xn      (f32), chunked parallel scan
    scan_pass1<<<dim3(4, 2, SCAN_P), 256, 0, stream>>>(xnW, deltaW, bcW, Alog, sEndW, PtotW);
    scan_mid<<<128, 256, 0, stream>>>(sEndW, PtotW, sInW);
    scan_pass2<<<dim3(4, 2, SCAN_P), 256, 0, stream>>>(x, xnW, deltaW, bcW, Alog, Dp, sInW, ssmW);
    // 5. normed = LN2(ssm_out)               (bf16)
    ln_kernel<<<4096, 256, 0, stream>>>(ssmW, ln2g, ln2b, nrmW);
    // 6. hff = gelu(normed @ W1^T + b1)      (bf16)
    gemm_bt<1><<<dim3(32, 32), 256, 0, stream>>>(nrmW, W1B, b1, hffW, nullptr, 4096, 4096, 1024, 1024, 1024);
    // 7a. FFN2 split-K=4 partial GEMMs       (bf16 partials, grid.z = split)
    gemm_bt<3><<<dim3(8, 32, 4), 256, 0, stream>>>(hffW, W2B, nullptr, ffn2p01, ffn2p23, 4096, 1024, 1024, 4096, 4096);
    // 7b. out = sum(partials) + b2 + ssm_out (f32)
    ffn2_reduce<<<4096, 256, 0, stream>>>(ffn2p01, ffn2p23, b2, ssmW, out);

    (void)in_sizes; (void)n_in; (void)out_size; (void)ws_size;
}

// Round 8
// 347.652 us; speedup vs baseline: 2.3646x; 1.1462x over previous
//
#include <hip/hip_runtime.h>
#include <cstdint>
#include <cstddef>

typedef unsigned short USHORT;
typedef __bf16 bf16x8 __attribute__((ext_vector_type(8)));
typedef float f32x4 __attribute__((ext_vector_type(4)));

__device__ __forceinline__ float b2f(USHORT u) {
    union { unsigned int i; float f; } v; v.i = ((unsigned int)u) << 16; return v.f;
}
__device__ __forceinline__ USHORT f2bf(float f) {
    union { float f; unsigned int i; } v; v.f = f;
    unsigned int u = v.i;
    unsigned int r = (u + 0x7FFFu + ((u >> 16) & 1u)) >> 16;
    return (USHORT)r;
}
__device__ __forceinline__ float fexp2(float x) { return __builtin_amdgcn_exp2f(x); }

__device__ __forceinline__ void gload_lds16(const void* g, void* l) {
    __builtin_amdgcn_global_load_lds(
        (const __attribute__((address_space(1))) void*)(uintptr_t)g,
        (__attribute__((address_space(3))) void*)(uint32_t)(uintptr_t)l,
        16, 0, 0);
}

// ---------------- f32 -> bf16 conversion (weights), 4 elems/thread ----------
__global__ __launch_bounds__(256)
void f2b_kernel(const float* __restrict__ src, USHORT* __restrict__ dst, int n)
{
    int i = (blockIdx.x * 256 + threadIdx.x) * 4;
    if (i < n) {
        float4 v = *(const float4*)(src + i);
        ushort4 o;
        o.x = f2bf(v.x); o.y = f2bf(v.y); o.z = f2bf(v.z); o.w = f2bf(v.w);
        *(ushort4*)(dst + i) = o;
    }
}

// ---------------- LayerNorm: f32 in -> bf16 out. 1 block/token, 256 thr ----
__global__ __launch_bounds__(256)
void ln_kernel(const float* __restrict__ inp, const float* __restrict__ g,
               const float* __restrict__ bsh, USHORT* __restrict__ out)
{
    const int tid = threadIdx.x;
    const size_t row = blockIdx.x;
    float4 t = ((const float4*)inp)[row * 256 + tid];
    float v[4] = { t.x, t.y, t.z, t.w };
    float s = v[0] + v[1] + v[2] + v[3];
    float sq = v[0]*v[0] + v[1]*v[1] + v[2]*v[2] + v[3]*v[3];
    #pragma unroll
    for (int off = 32; off; off >>= 1) { s += __shfl_down(s, off); sq += __shfl_down(sq, off); }
    __shared__ float red[8];
    const int wv = tid >> 6;
    if ((tid & 63) == 0) { red[wv] = s; red[wv + 4] = sq; }
    __syncthreads();
    const float S  = red[0] + red[1] + red[2] + red[3];
    const float SQ = red[4] + red[5] + red[6] + red[7];
    const float mu = S * (1.0f / 1024.0f);
    const float var = SQ * (1.0f / 1024.0f) - mu * mu;
    const float rs = rsqrtf(var + 1e-5f);
    float4 gv = ((const float4*)g)[tid];
    float4 bv = ((const float4*)bsh)[tid];
    ushort4 o;
    o.x = f2bf((v[0] - mu) * rs * gv.x + bv.x);
    o.y = f2bf((v[1] - mu) * rs * gv.y + bv.y);
    o.z = f2bf((v[2] - mu) * rs * gv.z + bv.z);
    o.w = f2bf((v[3] - mu) * rs * gv.w + bv.w);
    ((ushort4*)out)[row * 256 + tid] = o;
}

// ---------------- GEMM: C(M,N) = A(M,K) @ B(N,K)^T, bf16 MFMA, fused epilogue
// EPI 1: gelu (tanh form, native exp2/rcp) -> bf16 out
// EPI 3: split-K partial (blockIdx.z selects K-slice), raw bf16 partial out
// GROUP_M=8 pid swizzle; epilogue via LDS -> coalesced global stores.
template<int EPI>
__global__ __launch_bounds__(256)
void gemm_bt(const USHORT* __restrict__ A, const USHORT* __restrict__ B,
             const float* __restrict__ bias, void* __restrict__ outp,
             void* __restrict__ outp2, int M, int N, int K, int lda, int ldb)
{
    __shared__ __align__(16) unsigned char smem[17408];  // 16KB staging / 17KB epilogue
    USHORT* As = (USHORT*)smem;
    USHORT* Bs = (USHORT*)(smem + 8192);
    const int tid = threadIdx.x;
    const int lane = tid & 63;
    const int w = tid >> 6;
    const int wr = w >> 1, wc = w & 1;

    // GROUP_M=8 swizzle over the (gridDim.x x gridDim.y) tile grid
    const int nx = gridDim.x, ny = gridDim.y;
    const int pid = blockIdx.y * nx + blockIdx.x;
    const int npg = 8 * nx;
    const int gid = pid / npg;
    const int first = gid * 8;
    const int rem = ny - first;
    const int gsz = (rem < 8) ? rem : 8;
    const int py = first + (pid % npg) % gsz;
    const int px = (pid % npg) / gsz;
    const int tm = py * 128;
    const int tn = px * 128;

    USHORT* po = nullptr;
    if constexpr (EPI == 3) {
        const int z = blockIdx.z;
        A += (size_t)z * K;             // K-slice offset within row (lda=full K)
        B += (size_t)z * K;
        po = ((z < 2) ? (USHORT*)outp : (USHORT*)outp2) + (size_t)(z & 1) * M * N;
    }

    f32x4 acc[4][4];
    #pragma unroll
    for (int i = 0; i < 4; i++)
        #pragma unroll
        for (int j = 0; j < 4; j++) acc[i][j] = (f32x4){0.f, 0.f, 0.f, 0.f};

    const int srow = tid >> 2;          // 0..63
    const int scol = (tid & 3) * 8;     // 0,8,16,24
    const USHORT* gA0 = A + (size_t)(tm + srow) * lda + scol;
    const USHORT* gA1 = A + (size_t)(tm + 64 + srow) * lda + scol;
    const USHORT* gB0 = B + (size_t)(tn + srow) * ldb + scol;
    const USHORT* gB1 = B + (size_t)(tn + 64 + srow) * ldb + scol;
    USHORT* lA0 = As + w * 512;          // wave-uniform LDS bases
    USHORT* lA1 = As + 2048 + w * 512;
    USHORT* lB0 = Bs + w * 512;
    USHORT* lB1 = Bs + 2048 + w * 512;

    const int fr = lane & 15;
    const int fko = (lane >> 4) * 8;
    const int quad = lane >> 4;

    for (int k0 = 0; k0 < K; k0 += 32) {
        gload_lds16(gA0 + k0, lA0);
        gload_lds16(gA1 + k0, lA1);
        gload_lds16(gB0 + k0, lB0);
        gload_lds16(gB1 + k0, lB1);
        __syncthreads();
        bf16x8 af[4], bfr[4];
        #pragma unroll
        for (int i = 0; i < 4; i++) {
            af[i]  = *(const bf16x8*)(As + (wr * 64 + i * 16 + fr) * 32 + fko);
            bfr[i] = *(const bf16x8*)(Bs + (wc * 64 + i * 16 + fr) * 32 + fko);
        }
        #pragma unroll
        for (int i = 0; i < 4; i++)
            #pragma unroll
            for (int j = 0; j < 4; j++)
                acc[i][j] = __builtin_amdgcn_mfma_f32_16x16x32_bf16(af[i], bfr[j], acc[i][j], 0, 0, 0);
        __syncthreads();
    }

    // ---- epilogue: per-wave 16x64 f32 slices through LDS, coalesced stores
    float* eW = (float*)(smem + (size_t)w * 4352);   // 16 rows x 68 f32
    const int rr = lane >> 5;            // 0..1 (row within pair)
    const int cc = lane & 31;            // 0..31 (col pair)
    const int gcolb = tn + wc * 64;
    float2 bvv;
    if constexpr (EPI == 3) { bvv.x = 0.f; bvv.y = 0.f; }
    else bvv = *(const float2*)&bias[gcolb + cc * 2];

    #pragma unroll
    for (int i = 0; i < 4; i++) {
        #pragma unroll
        for (int j = 0; j < 4; j++)
            #pragma unroll
            for (int r = 0; r < 4; r++)
                eW[(quad * 4 + r) * 68 + j * 16 + fr] = acc[i][j][r];
        __syncthreads();
        const int grow0 = tm + wr * 64 + i * 16;
        #pragma unroll
        for (int rp = 0; rp < 8; rp++) {
            const int row = rp * 2 + rr;
            const float2 v = *(const float2*)&eW[row * 68 + cc * 2];
            const size_t gidx = (size_t)(grow0 + row) * N + gcolb + cc * 2;
            if constexpr (EPI == 1) {
                const float z0 = v.x + bvv.x, z1 = v.y + bvv.y;
                const float u0 = z0 * (0.7978845608f + 0.035677408f * z0 * z0);
                const float u1 = z1 * (0.7978845608f + 0.035677408f * z1 * z1);
                const float s0 = __builtin_amdgcn_rcpf(1.f + fexp2(2.885390082f * u0));
                const float s1 = __builtin_amdgcn_rcpf(1.f + fexp2(2.885390082f * u1));
                const float g0 = z0 * (1.f - s0), g1 = z1 * (1.f - s1);
                const uint32_t pk = (uint32_t)f2bf(g0) | ((uint32_t)f2bf(g1) << 16);
                *(uint32_t*)((USHORT*)outp + gidx) = pk;
            } else {
                const uint32_t pk = (uint32_t)f2bf(v.x) | ((uint32_t)f2bf(v.y) << 16);
                *(uint32_t*)(po + gidx) = pk;
            }
        }
        __syncthreads();
    }
}

// ---------------- delta split-K reduce: delta = softplus(p0+p1+bias), f32 ---
__global__ __launch_bounds__(256)
void delta_reduce(const USHORT* __restrict__ p, const float* __restrict__ bias,
                  float* __restrict__ out)
{
    const size_t PS = (size_t)4096 * 1024;
    const size_t i = ((size_t)blockIdx.x * 256 + threadIdx.x) * 4;
    ushort4 a = *(const ushort4*)(p + i);
    ushort4 b = *(const ushort4*)(p + PS + i);
    float4 bv = *(const float4*)(bias + (i & 1023));
    float z[4] = { b2f(a.x) + b2f(b.x) + bv.x, b2f(a.y) + b2f(b.y) + bv.y,
                   b2f(a.z) + b2f(b.z) + bv.z, b2f(a.w) + b2f(b.w) + bv.w };
    float4 o;
    o.x = (z[0] > 20.f) ? z[0] : 0.69314718f * __log2f(1.f + fexp2(z[0] * 1.44269504f));
    o.y = (z[1] > 20.f) ? z[1] : 0.69314718f * __log2f(1.f + fexp2(z[1] * 1.44269504f));
    o.z = (z[2] > 20.f) ? z[2] : 0.69314718f * __log2f(1.f + fexp2(z[2] * 1.44269504f));
    o.w = (z[3] > 20.f) ? z[3] : 0.69314718f * __log2f(1.f + fexp2(z[3] * 1.44269504f));
    *(float4*)(out + i) = o;
}

// ---------------- FFN2 split-K reduce: out = sum(partials) + bias + extra ---
__global__ __launch_bounds__(256)
void ffn2_reduce(const USHORT* __restrict__ p01, const USHORT* __restrict__ p23,
                 const float* __restrict__ bias, const float* __restrict__ extra,
                 float* __restrict__ out)
{
    const size_t PS = (size_t)4096 * 1024;      // one partial, elems
    const size_t i = ((size_t)blockIdx.x * 256 + threadIdx.x) * 4;
    ushort4 a = *(const ushort4*)(p01 + i);
    ushort4 b = *(const ushort4*)(p01 + PS + i);
    ushort4 c = *(const ushort4*)(p23 + i);
    ushort4 d = *(const ushort4*)(p23 + PS + i);
    float4 bv = *(const float4*)(bias + (i & 1023));
    float4 ev = *(const float4*)(extra + i);
    float4 o;
    o.x = b2f(a.x) + b2f(b.x) + b2f(c.x) + b2f(d.x) + bv.x + ev.x;
    o.y = b2f(a.y) + b2f(b.y) + b2f(c.y) + b2f(d.y) + bv.y + ev.y;
    o.z = b2f(a.z) + b2f(b.z) + b2f(c.z) + b2f(d.z) + bv.z + ev.z;
    o.w = b2f(a.w) + b2f(b.w) + b2f(c.w) + b2f(d.w) + bv.w + ev.w;
    *(float4*)(out + i) = o;
}

// ---------------- bc = xn @ Wbc^T + bbc via MFMA: 64 tokens/block ----------
// Old bc_kernel was VMEM-request bound: lanes read Wbc rows 4KB apart
// (32 cache lines per load). This version stages everything coalesced.
__global__ __launch_bounds__(256)
void bc_mfma(const USHORT* __restrict__ xn, const USHORT* __restrict__ WbcB,
             const float* __restrict__ bbc, float* __restrict__ bc)
{
    __shared__ __align__(16) USHORT As[64 * 32];   // 4 KB
    __shared__ __align__(16) USHORT Bs[32 * 32];   // 2 KB
    const int tid = threadIdx.x;
    const int lane = tid & 63;
    const int w = tid >> 6;
    const int tok0 = blockIdx.x * 64;

    const int srow = tid >> 2;           // 0..63
    const int scol = (tid & 3) * 8;
    const USHORT* gA = xn + (size_t)(tok0 + srow) * 1024 + scol;
    const USHORT* gB = WbcB + (size_t)srow * 1024 + scol;   // rows 0..31 used
    USHORT* lA = As + w * 512;           // wave-uniform base, lane*8 contiguous
    USHORT* lB = Bs + w * 512;           // waves 0,1 only

    const int fr = lane & 15;
    const int fko = (lane >> 4) * 8;
    const int quad = lane >> 4;

    f32x4 acc[2];
    acc[0] = (f32x4){0.f, 0.f, 0.f, 0.f};
    acc[1] = (f32x4){0.f, 0.f, 0.f, 0.f};

    for (int k0 = 0; k0 < 1024; k0 += 32) {
        gload_lds16(gA + k0, lA);
        if (w < 2) gload_lds16(gB + k0, lB);
        __syncthreads();
        bf16x8 af = *(const bf16x8*)(As + (w * 16 + fr) * 32 + fko);
        bf16x8 b0 = *(const bf16x8*)(Bs + (fr) * 32 + fko);
        bf16x8 b1 = *(const bf16x8*)(Bs + (16 + fr) * 32 + fko);
        acc[0] = __builtin_amdgcn_mfma_f32_16x16x32_bf16(af, b0, acc[0], 0, 0, 0);
        acc[1] = __builtin_amdgcn_mfma_f32_16x16x32_bf16(af, b1, acc[1], 0, 0, 0);
        __syncthreads();
    }

    #pragma unroll
    for (int j = 0; j < 2; j++) {
        const int col = j * 16 + fr;
        const float bv = bbc[col];
        #pragma unroll
        for (int r = 0; r < 4; r++) {
            const int row = tok0 + w * 16 + quad * 4 + r;
            bc[(size_t)row * 32 + col] = acc[j][r] + bv;
        }
    }
}

// ---------------- selective scan v3: chunked parallel, lane=h, n in regs ----
#define SCAN_P 64
#define SCAN_T 32

__global__ __launch_bounds__(256)
void scan_pass1(const USHORT* __restrict__ xn, const float* __restrict__ delta,
                const float* __restrict__ bc, const float* __restrict__ Alog,
                float* __restrict__ sEnd, float* __restrict__ Ptot)
{
    const int tid = threadIdx.x;
    const int h = blockIdx.x * 256 + tid;
    const int b = blockIdx.y;
    const int p = blockIdx.z;
    const size_t tok0 = (size_t)b * 2048 + p * SCAN_T;

    __shared__ __align__(16) float sBC[SCAN_T][32];
    {
        int t = tid >> 3, q = (tid & 7) * 4;
        *(float4*)&sBC[t][q] = *(const float4*)(bc + (tok0 + t) * 32 + q);
    }

    float en[16], s[16], P[16];
    #pragma unroll
    for (int k = 0; k < 4; k++) {
        float4 a = *(const float4*)(Alog + h * 16 + k * 4);
        en[k*4+0] = -__expf(a.x) * 1.44269504f;
        en[k*4+1] = -__expf(a.y) * 1.44269504f;
        en[k*4+2] = -__expf(a.z) * 1.44269504f;
        en[k*4+3] = -__expf(a.w) * 1.44269504f;
    }
    #pragma unroll
    for (int n = 0; n < 16; n++) { s[n] = 0.f; P[n] = 1.f; }
    __syncthreads();

    const float* dp = delta + tok0 * 1024 + h;
    const USHORT* xp = xn + tok0 * 1024 + h;
    float d_c = dp[0];
    USHORT x_c = xp[0];
    for (int t = 0; t < SCAN_T; ++t) {
        const int tn = (t < SCAN_T - 1) ? t + 1 : t;
        float d_n = dp[(size_t)tn * 1024];
        USHORT x_n = xp[(size_t)tn * 1024];
        const float dx = d_c * b2f(x_c);
        #pragma unroll
        for (int k = 0; k < 4; k++) {
            float4 Bv = *(const float4*)&sBC[t][k*4];
            float bb[4] = { Bv.x, Bv.y, Bv.z, Bv.w };
            #pragma unroll
            for (int j = 0; j < 4; j++) {
                const int n = k*4 + j;
                const float dA = fexp2(d_c * en[n]);
                s[n] = fmaf(dA, s[n], dx * bb[j]);
                P[n] *= dA;
            }
        }
        d_c = d_n; x_c = x_n;
    }

    const size_t off = (size_t)p * 32768 + ((size_t)b * 1024 + h) * 16;
    #pragma unroll
    for (int k = 0; k < 4; k++) {
        *(float4*)(sEnd + off + k*4) = (float4){ s[k*4], s[k*4+1], s[k*4+2], s[k*4+3] };
        *(float4*)(Ptot + off + k*4) = (float4){ P[k*4], P[k*4+1], P[k*4+2], P[k*4+3] };
    }
}

__global__ __launch_bounds__(256)
void scan_mid(const float* __restrict__ sEnd, const float* __restrict__ Ptot,
              float* __restrict__ sIn)
{
    const int L = blockIdx.x * 256 + threadIdx.x;   // 0..32767 = (b*1024+h)*16+n
    float s = 0.f;
    #pragma unroll 8
    for (int p = 0; p < SCAN_P; ++p) {
        const size_t off = (size_t)p * 32768 + L;
        sIn[off] = s;
        s = fmaf(Ptot[off], s, sEnd[off]);
    }
}

__global__ __launch_bounds__(256)
void scan_pass2(const float* __restrict__ x, const USHORT* __restrict__ xn,
                const float* __restrict__ delta, const float* __restrict__ bc,
                const float* __restrict__ Alog, const float* __restrict__ Dp,
                const float* __restrict__ sIn, float* __restrict__ ssm)
{
    const int tid = threadIdx.x;
    const int h = blockIdx.x * 256 + tid;
    const int b = blockIdx.y;
    const int p = blockIdx.z;
    const size_t tok0 = (size_t)b * 2048 + p * SCAN_T;

    __shared__ __align__(16) float sBC[SCAN_T][32];
    {
        int t = tid >> 3, q = (tid & 7) * 4;
        *(float4*)&sBC[t][q] = *(const float4*)(bc + (tok0 + t) * 32 + q);
    }

    float en[16], s[16];
    #pragma unroll
    for (int k = 0; k < 4; k++) {
        float4 a = *(const float4*)(Alog + h * 16 + k * 4);
        en[k*4+0] = -__expf(a.x) * 1.44269504f;
        en[k*4+1] = -__expf(a.y) * 1.44269504f;
        en[k*4+2] = -__expf(a.z) * 1.44269504f;
        en[k*4+3] = -__expf(a.w) * 1.44269504f;
    }
    const size_t off = (size_t)p * 32768 + ((size_t)b * 1024 + h) * 16;
    #pragma unroll
    for (int k = 0; k < 4; k++) {
        float4 v = *(const float4*)(sIn + off + k*4);
        s[k*4] = v.x; s[k*4+1] = v.y; s[k*4+2] = v.z; s[k*4+3] = v.w;
    }
    const float Dv = Dp[h];
    __syncthreads();

    const float* dp = delta + tok0 * 1024 + h;
    const USHORT* xp = xn + tok0 * 1024 + h;
    const float* xrp = x + tok0 * 1024 + h;
    float* op = ssm + tok0 * 1024 + h;

    float d_c = dp[0];
    USHORT x_c = xp[0];
    float xr_c = xrp[0];
    for (int t = 0; t < SCAN_T; ++t) {
        const int tn = (t < SCAN_T - 1) ? t + 1 : t;
        float d_n = dp[(size_t)tn * 1024];
        USHORT x_n = xp[(size_t)tn * 1024];
        float xr_n = xrp[(size_t)tn * 1024];
        const float xv = b2f(x_c);
        const float dx = d_c * xv;
        float y = 0.f;
        #pragma unroll
        for (int k = 0; k < 4; k++) {
            float4 Bv = *(const float4*)&sBC[t][k*4];
            float4 Cv = *(const float4*)&sBC[t][16 + k*4];
            float bb[4] = { Bv.x, Bv.y, Bv.z, Bv.w };
            float cc[4] = { Cv.x, Cv.y, Cv.z, Cv.w };
            #pragma unroll
            for (int j = 0; j < 4; j++) {
                const int n = k*4 + j;
                const float dA = fexp2(d_c * en[n]);
                s[n] = fmaf(dA, s[n], dx * bb[j]);
                y = fmaf(cc[j], s[n], y);
            }
        }
        op[(size_t)t * 1024] = xr_c + y + Dv * xv;
        d_c = d_n; x_c = x_n; xr_c = xr_n;
    }
}

extern "C" void kernel_launch(void* const* d_in, const int* in_sizes, int n_in,
                              void* d_out, int out_size, void* d_ws, size_t ws_size,
                              hipStream_t stream)
{
    const float* x    = (const float*)d_in[0];
    const float* ln1g = (const float*)d_in[1];
    const float* ln1b = (const float*)d_in[2];
    const float* Wd   = (const float*)d_in[3];
    const float* bd   = (const float*)d_in[4];
    const float* Wbc  = (const float*)d_in[5];
    const float* bbc  = (const float*)d_in[6];
    const float* Alog = (const float*)d_in[7];
    const float* Dp   = (const float*)d_in[8];
    const float* ln2g = (const float*)d_in[9];
    const float* ln2b = (const float*)d_in[10];
    const float* W1   = (const float*)d_in[11];
    const float* b1   = (const float*)d_in[12];
    const float* W2   = (const float*)d_in[13];
    const float* b2   = (const float*)d_in[14];
    float* out = (float*)d_out;

    char* ws = (char*)d_ws;
    const size_t MB = 1024 * 1024;
    float*  deltaW = (float*)(ws + 0);            // 16 MiB (4096x1024 f32)
    float*  ssmW   = (float*)(ws + 16 * MB);      // 16 MiB (4096x1024 f32)
    USHORT* xnW    = (USHORT*)(ws + 32 * MB);     //  8 MiB (4096x1024 bf16)
    USHORT* nrmW   = (USHORT*)(ws + 40 * MB);     //  8 MiB (4096x1024 bf16)
    USHORT* hffW   = (USHORT*)(ws + 48 * MB);     // 32 MiB (4096x4096 bf16)
    float*  bcW    = (float*)(ws + 80 * MB);      // 512 KiB (4096x32 f32)
    USHORT* WdB    = (USHORT*)(ws + 81 * MB);     //  2 MiB (1024x1024 bf16)
    USHORT* W1B    = (USHORT*)(ws + 83 * MB);     //  8 MiB (4096x1024 bf16)
    USHORT* W2B    = (USHORT*)(ws + 91 * MB);     //  8 MiB (1024x4096 bf16)
    USHORT* WbcB   = (USHORT*)(ws + 99 * MB);     // 64 KiB (32x1024 bf16)
    // delta split-K partials alias hffW (dead until step 6): 2 x 8 MiB
    USHORT* dpart  = (USHORT*)(ws + 48 * MB);
    // scan scratch aliases hffW too (delta reduce finishes first): 3 x 8 MiB
    float*  sEndW  = (float*)(ws + 48 * MB);
    float*  PtotW  = (float*)(ws + 56 * MB);
    float*  sInW   = (float*)(ws + 64 * MB);
    // FFN2 split-K partials alias deltaW (splits 0,1) and xnW/nrmW (splits 2,3)
    USHORT* ffn2p01 = (USHORT*)(ws + 0);          // 16 MiB: 2 x 4096x1024 bf16
    USHORT* ffn2p23 = (USHORT*)(ws + 32 * MB);    // 16 MiB: 2 x 4096x1024 bf16

    // 0. convert weights f32 -> bf16
    f2b_kernel<<<1024, 256, 0, stream>>>(Wd, WdB, 1024 * 1024);
    f2b_kernel<<<4096, 256, 0, stream>>>(W1, W1B, 4096 * 1024);
    f2b_kernel<<<4096, 256, 0, stream>>>(W2, W2B, 1024 * 4096);
    f2b_kernel<<<32, 256, 0, stream>>>(Wbc, WbcB, 32 * 1024);
    // 1. xn = LN1(x)                         (bf16)
    ln_kernel<<<4096, 256, 0, stream>>>(x, ln1g, ln1b, xnW);
    // 2a. delta split-K=2 partial GEMMs      (bf16 partials)
    gemm_bt<3><<<dim3(8, 32, 2), 256, 0, stream>>>(xnW, WdB, nullptr, dpart, nullptr, 4096, 1024, 512, 1024, 1024);
    // 2b. delta = softplus(p0+p1+bd)         (f32)
    delta_reduce<<<4096, 256, 0, stream>>>(dpart, bd, deltaW);
    // 3. bc = xn @ Wbc^T + bbc               (f32), MFMA micro-GEMM
    bc_mfma<<<64, 256, 0, stream>>>(xnW, WbcB, bbc, bcW);
    // 4. ssm_out = x + scan(...) + D*xn      (f32), chunked parallel scan
    scan_pass1<<<dim3(4, 2, SCAN_P), 256, 0, stream>>>(xnW, deltaW, bcW, Alog, sEndW, PtotW);
    scan_mid<<<128, 256, 0, stream>>>(sEndW, PtotW, sInW);
    scan_pass2<<<dim3(4, 2, SCAN_P), 256, 0, stream>>>(x, xnW, deltaW, bcW, Alog, Dp, sInW, ssmW);
    // 5. normed = LN2(ssm_out)               (bf16)
    ln_kernel<<<4096, 256, 0, stream>>>(ssmW, ln2g, ln2b, nrmW);
    // 6. hff = gelu(normed @ W1^T + b1)      (bf16)
    gemm_bt<1><<<dim3(32, 32), 256, 0, stream>>>(nrmW, W1B, b1, hffW, nullptr, 4096, 4096, 1024, 1024, 1024);
    // 7a. FFN2 split-K=4 partial GEMMs       (bf16 partials, grid.z = split)
    gemm_bt<3><<<dim3(8, 32, 4), 256, 0, stream>>>(hffW, W2B, nullptr, ffn2p01, ffn2p23, 4096, 1024, 1024, 4096, 4096);
    // 7b. out = sum(partials) + b2 + ssm_out (f32)
    ffn2_reduce<<<4096, 256, 0, stream>>>(ffn2p01, ffn2p23, b2, ssmW, out);

    (void)in_sizes; (void)n_in; (void)out_size; (void)ws_size;
}

// Round 9
// 333.269 us; speedup vs baseline: 2.4667x; 1.0432x over previous
//
#include <hip/hip_runtime.h>
#include <cstdint>
#include <cstddef>

typedef unsigned short USHORT;
typedef __bf16 bf16x8 __attribute__((ext_vector_type(8)));
typedef float f32x4 __attribute__((ext_vector_type(4)));

__device__ __forceinline__ float b2f(USHORT u) {
    union { unsigned int i; float f; } v; v.i = ((unsigned int)u) << 16; return v.f;
}
__device__ __forceinline__ USHORT f2bf(float f) {
    union { float f; unsigned int i; } v; v.f = f;
    unsigned int u = v.i;
    unsigned int r = (u + 0x7FFFu + ((u >> 16) & 1u)) >> 16;
    return (USHORT)r;
}
__device__ __forceinline__ float fexp2(float x) { return __builtin_amdgcn_exp2f(x); }

__device__ __forceinline__ void gload_lds16(const void* g, void* l) {
    __builtin_amdgcn_global_load_lds(
        (const __attribute__((address_space(1))) void*)(uintptr_t)g,
        (__attribute__((address_space(3))) void*)(uint32_t)(uintptr_t)l,
        16, 0, 0);
}

// ---------------- f32 -> bf16 conversion (weights), 4 elems/thread ----------
__global__ __launch_bounds__(256)
void f2b_kernel(const float* __restrict__ src, USHORT* __restrict__ dst, int n)
{
    int i = (blockIdx.x * 256 + threadIdx.x) * 4;
    if (i < n) {
        float4 v = *(const float4*)(src + i);
        ushort4 o;
        o.x = f2bf(v.x); o.y = f2bf(v.y); o.z = f2bf(v.z); o.w = f2bf(v.w);
        *(ushort4*)(dst + i) = o;
    }
}

// ---------------- LayerNorm: f32 in -> bf16 out. 1 block/token, 256 thr ----
__global__ __launch_bounds__(256)
void ln_kernel(const float* __restrict__ inp, const float* __restrict__ g,
               const float* __restrict__ bsh, USHORT* __restrict__ out)
{
    const int tid = threadIdx.x;
    const size_t row = blockIdx.x;
    float4 t = ((const float4*)inp)[row * 256 + tid];
    float v[4] = { t.x, t.y, t.z, t.w };
    float s = v[0] + v[1] + v[2] + v[3];
    float sq = v[0]*v[0] + v[1]*v[1] + v[2]*v[2] + v[3]*v[3];
    #pragma unroll
    for (int off = 32; off; off >>= 1) { s += __shfl_down(s, off); sq += __shfl_down(sq, off); }
    __shared__ float red[8];
    const int wv = tid >> 6;
    if ((tid & 63) == 0) { red[wv] = s; red[wv + 4] = sq; }
    __syncthreads();
    const float S  = red[0] + red[1] + red[2] + red[3];
    const float SQ = red[4] + red[5] + red[6] + red[7];
    const float mu = S * (1.0f / 1024.0f);
    const float var = SQ * (1.0f / 1024.0f) - mu * mu;
    const float rs = rsqrtf(var + 1e-5f);
    float4 gv = ((const float4*)g)[tid];
    float4 bv = ((const float4*)bsh)[tid];
    ushort4 o;
    o.x = f2bf((v[0] - mu) * rs * gv.x + bv.x);
    o.y = f2bf((v[1] - mu) * rs * gv.y + bv.y);
    o.z = f2bf((v[2] - mu) * rs * gv.z + bv.z);
    o.w = f2bf((v[3] - mu) * rs * gv.w + bv.w);
    ((ushort4*)out)[row * 256 + tid] = o;
}

// ---------------- GEMM: C(M,N) = A(M,K) @ B(N,K)^T, bf16 MFMA, fused epilogue
// EPI 1: gelu (tanh form, native exp2/rcp) -> bf16 out
// EPI 3: split-K partial (blockIdx.z selects K-slice), raw bf16 partial out
// BK=64 as two independent BK=32 sub-tiles (As0/Bs0 @k0, As1/Bs1 @k0+32):
// read-side layout per half identical to the verified BK=32 pattern, but
// one barrier pair per 64 k -> half the vmcnt(0)+barrier drains, 32 MFMA
// per barrier (AITER-style density). LDS 32KB staging (5 blocks/CU cap).
// GROUP_M=8 pid swizzle; epilogue via LDS -> coalesced global stores.
template<int EPI>
__global__ __launch_bounds__(256)
void gemm_bt(const USHORT* __restrict__ A, const USHORT* __restrict__ B,
             const float* __restrict__ bias, void* __restrict__ outp,
             void* __restrict__ outp2, int M, int N, int K, int lda, int ldb)
{
    __shared__ __align__(16) unsigned char smem[32768];  // 4 x 8KB staging; epilogue reuses 17KB
    USHORT* As = (USHORT*)smem;                  // As0 @0, Bs0 @8KB, As1 @16KB, Bs1 @24KB
    USHORT* Bs = (USHORT*)(smem + 8192);
    const int tid = threadIdx.x;
    const int lane = tid & 63;
    const int w = tid >> 6;
    const int wr = w >> 1, wc = w & 1;

    // GROUP_M=8 swizzle over the (gridDim.x x gridDim.y) tile grid
    const int nx = gridDim.x, ny = gridDim.y;
    const int pid = blockIdx.y * nx + blockIdx.x;
    const int npg = 8 * nx;
    const int gid = pid / npg;
    const int first = gid * 8;
    const int rem = ny - first;
    const int gsz = (rem < 8) ? rem : 8;
    const int py = first + (pid % npg) % gsz;
    const int px = (pid % npg) / gsz;
    const int tm = py * 128;
    const int tn = px * 128;

    USHORT* po = nullptr;
    if constexpr (EPI == 3) {
        const int z = blockIdx.z;
        A += (size_t)z * K;             // K-slice offset within row (lda=full K)
        B += (size_t)z * K;
        po = ((z < 2) ? (USHORT*)outp : (USHORT*)outp2) + (size_t)(z & 1) * M * N;
    }

    f32x4 acc[4][4];
    #pragma unroll
    for (int i = 0; i < 4; i++)
        #pragma unroll
        for (int j = 0; j < 4; j++) acc[i][j] = (f32x4){0.f, 0.f, 0.f, 0.f};

    const int srow = tid >> 2;          // 0..63
    const int scol = (tid & 3) * 8;     // 0,8,16,24
    const USHORT* gA0 = A + (size_t)(tm + srow) * lda + scol;
    const USHORT* gA1 = A + (size_t)(tm + 64 + srow) * lda + scol;
    const USHORT* gB0 = B + (size_t)(tn + srow) * ldb + scol;
    const USHORT* gB1 = B + (size_t)(tn + 64 + srow) * ldb + scol;
    USHORT* lA0 = As + w * 512;          // wave-uniform LDS bases (half 0)
    USHORT* lA1 = As + 2048 + w * 512;
    USHORT* lB0 = Bs + w * 512;
    USHORT* lB1 = Bs + 2048 + w * 512;
    // half-1 buffers live +16KB (= +8192 USHORT elems) above half-0

    const int fr = lane & 15;
    const int fko = (lane >> 4) * 8;
    const int quad = lane >> 4;

    for (int k0 = 0; k0 < K; k0 += 64) {
        gload_lds16(gA0 + k0, lA0);
        gload_lds16(gA1 + k0, lA1);
        gload_lds16(gB0 + k0, lB0);
        gload_lds16(gB1 + k0, lB1);
        gload_lds16(gA0 + k0 + 32, lA0 + 8192);
        gload_lds16(gA1 + k0 + 32, lA1 + 8192);
        gload_lds16(gB0 + k0 + 32, lB0 + 8192);
        gload_lds16(gB1 + k0 + 32, lB1 + 8192);
        __syncthreads();
        #pragma unroll
        for (int h = 0; h < 2; h++) {
            const USHORT* Ah = As + h * 8192;
            const USHORT* Bh = Bs + h * 8192;
            bf16x8 af[4], bfr[4];
            #pragma unroll
            for (int i = 0; i < 4; i++) {
                af[i]  = *(const bf16x8*)(Ah + (wr * 64 + i * 16 + fr) * 32 + fko);
                bfr[i] = *(const bf16x8*)(Bh + (wc * 64 + i * 16 + fr) * 32 + fko);
            }
            #pragma unroll
            for (int i = 0; i < 4; i++)
                #pragma unroll
                for (int j = 0; j < 4; j++)
                    acc[i][j] = __builtin_amdgcn_mfma_f32_16x16x32_bf16(af[i], bfr[j], acc[i][j], 0, 0, 0);
        }
        __syncthreads();
    }

    // ---- epilogue: per-wave 16x64 f32 slices through LDS, coalesced stores
    float* eW = (float*)(smem + (size_t)w * 4352);   // 16 rows x 68 f32
    const int rr = lane >> 5;            // 0..1 (row within pair)
    const int cc = lane & 31;            // 0..31 (col pair)
    const int gcolb = tn + wc * 64;
    float2 bvv;
    if constexpr (EPI == 3) { bvv.x = 0.f; bvv.y = 0.f; }
    else bvv = *(const float2*)&bias[gcolb + cc * 2];

    #pragma unroll
    for (int i = 0; i < 4; i++) {
        #pragma unroll
        for (int j = 0; j < 4; j++)
            #pragma unroll
            for (int r = 0; r < 4; r++)
                eW[(quad * 4 + r) * 68 + j * 16 + fr] = acc[i][j][r];
        __syncthreads();
        const int grow0 = tm + wr * 64 + i * 16;
        #pragma unroll
        for (int rp = 0; rp < 8; rp++) {
            const int row = rp * 2 + rr;
            const float2 v = *(const float2*)&eW[row * 68 + cc * 2];
            const size_t gidx = (size_t)(grow0 + row) * N + gcolb + cc * 2;
            if constexpr (EPI == 1) {
                const float z0 = v.x + bvv.x, z1 = v.y + bvv.y;
                const float u0 = z0 * (0.7978845608f + 0.035677408f * z0 * z0);
                const float u1 = z1 * (0.7978845608f + 0.035677408f * z1 * z1);
                const float s0 = __builtin_amdgcn_rcpf(1.f + fexp2(2.885390082f * u0));
                const float s1 = __builtin_amdgcn_rcpf(1.f + fexp2(2.885390082f * u1));
                const float g0 = z0 * (1.f - s0), g1 = z1 * (1.f - s1);
                const uint32_t pk = (uint32_t)f2bf(g0) | ((uint32_t)f2bf(g1) << 16);
                *(uint32_t*)((USHORT*)outp + gidx) = pk;
            } else {
                const uint32_t pk = (uint32_t)f2bf(v.x) | ((uint32_t)f2bf(v.y) << 16);
                *(uint32_t*)(po + gidx) = pk;
            }
        }
        __syncthreads();
    }
}

// ---------------- delta split-K reduce: delta = softplus(p0+p1+bias), f32 ---
__global__ __launch_bounds__(256)
void delta_reduce(const USHORT* __restrict__ p, const float* __restrict__ bias,
                  float* __restrict__ out)
{
    const size_t PS = (size_t)4096 * 1024;
    const size_t i = ((size_t)blockIdx.x * 256 + threadIdx.x) * 4;
    ushort4 a = *(const ushort4*)(p + i);
    ushort4 b = *(const ushort4*)(p + PS + i);
    float4 bv = *(const float4*)(bias + (i & 1023));
    float z[4] = { b2f(a.x) + b2f(b.x) + bv.x, b2f(a.y) + b2f(b.y) + bv.y,
                   b2f(a.z) + b2f(b.z) + bv.z, b2f(a.w) + b2f(b.w) + bv.w };
    float4 o;
    o.x = (z[0] > 20.f) ? z[0] : 0.69314718f * __log2f(1.f + fexp2(z[0] * 1.44269504f));
    o.y = (z[1] > 20.f) ? z[1] : 0.69314718f * __log2f(1.f + fexp2(z[1] * 1.44269504f));
    o.z = (z[2] > 20.f) ? z[2] : 0.69314718f * __log2f(1.f + fexp2(z[2] * 1.44269504f));
    o.w = (z[3] > 20.f) ? z[3] : 0.69314718f * __log2f(1.f + fexp2(z[3] * 1.44269504f));
    *(float4*)(out + i) = o;
}

// ---------------- FFN2 split-K reduce: out = sum(partials) + bias + extra ---
__global__ __launch_bounds__(256)
void ffn2_reduce(const USHORT* __restrict__ p01, const USHORT* __restrict__ p23,
                 const float* __restrict__ bias, const float* __restrict__ extra,
                 float* __restrict__ out)
{
    const size_t PS = (size_t)4096 * 1024;      // one partial, elems
    const size_t i = ((size_t)blockIdx.x * 256 + threadIdx.x) * 4;
    ushort4 a = *(const ushort4*)(p01 + i);
    ushort4 b = *(const ushort4*)(p01 + PS + i);
    ushort4 c = *(const ushort4*)(p23 + i);
    ushort4 d = *(const ushort4*)(p23 + PS + i);
    float4 bv = *(const float4*)(bias + (i & 1023));
    float4 ev = *(const float4*)(extra + i);
    float4 o;
    o.x = b2f(a.x) + b2f(b.x) + b2f(c.x) + b2f(d.x) + bv.x + ev.x;
    o.y = b2f(a.y) + b2f(b.y) + b2f(c.y) + b2f(d.y) + bv.y + ev.y;
    o.z = b2f(a.z) + b2f(b.z) + b2f(c.z) + b2f(d.z) + bv.z + ev.z;
    o.w = b2f(a.w) + b2f(b.w) + b2f(c.w) + b2f(d.w) + bv.w + ev.w;
    *(float4*)(out + i) = o;
}

// ---------------- bc = xn @ Wbc^T + bbc via MFMA: 64 tokens/block ----------
__global__ __launch_bounds__(256)
void bc_mfma(const USHORT* __restrict__ xn, const USHORT* __restrict__ WbcB,
             const float* __restrict__ bbc, float* __restrict__ bc)
{
    __shared__ __align__(16) USHORT As[64 * 32];   // 4 KB
    __shared__ __align__(16) USHORT Bs[32 * 32];   // 2 KB
    const int tid = threadIdx.x;
    const int lane = tid & 63;
    const int w = tid >> 6;
    const int tok0 = blockIdx.x * 64;

    const int srow = tid >> 2;           // 0..63
    const int scol = (tid & 3) * 8;
    const USHORT* gA = xn + (size_t)(tok0 + srow) * 1024 + scol;
    const USHORT* gB = WbcB + (size_t)srow * 1024 + scol;   // rows 0..31 used
    USHORT* lA = As + w * 512;           // wave-uniform base, lane*8 contiguous
    USHORT* lB = Bs + w * 512;           // waves 0,1 only

    const int fr = lane & 15;
    const int fko = (lane >> 4) * 8;
    const int quad = lane >> 4;

    f32x4 acc[2];
    acc[0] = (f32x4){0.f, 0.f, 0.f, 0.f};
    acc[1] = (f32x4){0.f, 0.f, 0.f, 0.f};

    for (int k0 = 0; k0 < 1024; k0 += 32) {
        gload_lds16(gA + k0, lA);
        if (w < 2) gload_lds16(gB + k0, lB);
        __syncthreads();
        bf16x8 af = *(const bf16x8*)(As + (w * 16 + fr) * 32 + fko);
        bf16x8 b0 = *(const bf16x8*)(Bs + (fr) * 32 + fko);
        bf16x8 b1 = *(const bf16x8*)(Bs + (16 + fr) * 32 + fko);
        acc[0] = __builtin_amdgcn_mfma_f32_16x16x32_bf16(af, b0, acc[0], 0, 0, 0);
        acc[1] = __builtin_amdgcn_mfma_f32_16x16x32_bf16(af, b1, acc[1], 0, 0, 0);
        __syncthreads();
    }

    #pragma unroll
    for (int j = 0; j < 2; j++) {
        const int col = j * 16 + fr;
        const float bv = bbc[col];
        #pragma unroll
        for (int r = 0; r < 4; r++) {
            const int row = tok0 + w * 16 + quad * 4 + r;
            bc[(size_t)row * 32 + col] = acc[j][r] + bv;
        }
    }
}

// ---------------- selective scan v3: chunked parallel, lane=h, n in regs ----
#define SCAN_P 64
#define SCAN_T 32

__global__ __launch_bounds__(256)
void scan_pass1(const USHORT* __restrict__ xn, const float* __restrict__ delta,
                const float* __restrict__ bc, const float* __restrict__ Alog,
                float* __restrict__ sEnd, float* __restrict__ Ptot)
{
    const int tid = threadIdx.x;
    const int h = blockIdx.x * 256 + tid;
    const int b = blockIdx.y;
    const int p = blockIdx.z;
    const size_t tok0 = (size_t)b * 2048 + p * SCAN_T;

    __shared__ __align__(16) float sBC[SCAN_T][32];
    {
        int t = tid >> 3, q = (tid & 7) * 4;
        *(float4*)&sBC[t][q] = *(const float4*)(bc + (tok0 + t) * 32 + q);
    }

    float en[16], s[16], P[16];
    #pragma unroll
    for (int k = 0; k < 4; k++) {
        float4 a = *(const float4*)(Alog + h * 16 + k * 4);
        en[k*4+0] = -__expf(a.x) * 1.44269504f;
        en[k*4+1] = -__expf(a.y) * 1.44269504f;
        en[k*4+2] = -__expf(a.z) * 1.44269504f;
        en[k*4+3] = -__expf(a.w) * 1.44269504f;
    }
    #pragma unroll
    for (int n = 0; n < 16; n++) { s[n] = 0.f; P[n] = 1.f; }
    __syncthreads();

    const float* dp = delta + tok0 * 1024 + h;
    const USHORT* xp = xn + tok0 * 1024 + h;
    float d_c = dp[0];
    USHORT x_c = xp[0];
    for (int t = 0; t < SCAN_T; ++t) {
        const int tn = (t < SCAN_T - 1) ? t + 1 : t;
        float d_n = dp[(size_t)tn * 1024];
        USHORT x_n = xp[(size_t)tn * 1024];
        const float dx = d_c * b2f(x_c);
        #pragma unroll
        for (int k = 0; k < 4; k++) {
            float4 Bv = *(const float4*)&sBC[t][k*4];
            float bb[4] = { Bv.x, Bv.y, Bv.z, Bv.w };
            #pragma unroll
            for (int j = 0; j < 4; j++) {
                const int n = k*4 + j;
                const float dA = fexp2(d_c * en[n]);
                s[n] = fmaf(dA, s[n], dx * bb[j]);
                P[n] *= dA;
            }
        }
        d_c = d_n; x_c = x_n;
    }

    const size_t off = (size_t)p * 32768 + ((size_t)b * 1024 + h) * 16;
    #pragma unroll
    for (int k = 0; k < 4; k++) {
        *(float4*)(sEnd + off + k*4) = (float4){ s[k*4], s[k*4+1], s[k*4+2], s[k*4+3] };
        *(float4*)(Ptot + off + k*4) = (float4){ P[k*4], P[k*4+1], P[k*4+2], P[k*4+3] };
    }
}

__global__ __launch_bounds__(256)
void scan_mid(const float* __restrict__ sEnd, const float* __restrict__ Ptot,
              float* __restrict__ sIn)
{
    const int L = blockIdx.x * 256 + threadIdx.x;   // 0..32767 = (b*1024+h)*16+n
    float s = 0.f;
    #pragma unroll 8
    for (int p = 0; p < SCAN_P; ++p) {
        const size_t off = (size_t)p * 32768 + L;
        sIn[off] = s;
        s = fmaf(Ptot[off], s, sEnd[off]);
    }
}

__global__ __launch_bounds__(256)
void scan_pass2(const float* __restrict__ x, const USHORT* __restrict__ xn,
                const float* __restrict__ delta, const float* __restrict__ bc,
                const float* __restrict__ Alog, const float* __restrict__ Dp,
                const float* __restrict__ sIn, float* __restrict__ ssm)
{
    const int tid = threadIdx.x;
    const int h = blockIdx.x * 256 + tid;
    const int b = blockIdx.y;
    const int p = blockIdx.z;
    const size_t tok0 = (size_t)b * 2048 + p * SCAN_T;

    __shared__ __align__(16) float sBC[SCAN_T][32];
    {
        int t = tid >> 3, q = (tid & 7) * 4;
        *(float4*)&sBC[t][q] = *(const float4*)(bc + (tok0 + t) * 32 + q);
    }

    float en[16], s[16];
    #pragma unroll
    for (int k = 0; k < 4; k++) {
        float4 a = *(const float4*)(Alog + h * 16 + k * 4);
        en[k*4+0] = -__expf(a.x) * 1.44269504f;
        en[k*4+1] = -__expf(a.y) * 1.44269504f;
        en[k*4+2] = -__expf(a.z) * 1.44269504f;
        en[k*4+3] = -__expf(a.w) * 1.44269504f;
    }
    const size_t off = (size_t)p * 32768 + ((size_t)b * 1024 + h) * 16;
    #pragma unroll
    for (int k = 0; k < 4; k++) {
        float4 v = *(const float4*)(sIn + off + k*4);
        s[k*4] = v.x; s[k*4+1] = v.y; s[k*4+2] = v.z; s[k*4+3] = v.w;
    }
    const float Dv = Dp[h];
    __syncthreads();

    const float* dp = delta + tok0 * 1024 + h;
    const USHORT* xp = xn + tok0 * 1024 + h;
    const float* xrp = x + tok0 * 1024 + h;
    float* op = ssm + tok0 * 1024 + h;

    float d_c = dp[0];
    USHORT x_c = xp[0];
    float xr_c = xrp[0];
    for (int t = 0; t < SCAN_T; ++t) {
        const int tn = (t < SCAN_T - 1) ? t + 1 : t;
        float d_n = dp[(size_t)tn * 1024];
        USHORT x_n = xp[(size_t)tn * 1024];
        float xr_n = xrp[(size_t)tn * 1024];
        const float xv = b2f(x_c);
        const float dx = d_c * xv;
        float y = 0.f;
        #pragma unroll
        for (int k = 0; k < 4; k++) {
            float4 Bv = *(const float4*)&sBC[t][k*4];
            float4 Cv = *(const float4*)&sBC[t][16 + k*4];
            float bb[4] = { Bv.x, Bv.y, Bv.z, Bv.w };
            float cc[4] = { Cv.x, Cv.y, Cv.z, Cv.w };
            #pragma unroll
            for (int j = 0; j < 4; j++) {
                const int n = k*4 + j;
                const float dA = fexp2(d_c * en[n]);
                s[n] = fmaf(dA, s[n], dx * bb[j]);
                y = fmaf(cc[j], s[n], y);
            }
        }
        op[(size_t)t * 1024] = xr_c + y + Dv * xv;
        d_c = d_n; x_c = x_n; xr_c = xr_n;
    }
}

extern "C" void kernel_launch(void* const* d_in, const int* in_sizes, int n_in,
                              void* d_out, int out_size, void* d_ws, size_t ws_size,
                              hipStream_t stream)
{
    const float* x    = (const float*)d_in[0];
    const float* ln1g = (const float*)d_in[1];
    const float* ln1b = (const float*)d_in[2];
    const float* Wd   = (const float*)d_in[3];
    const float* bd   = (const float*)d_in[4];
    const float* Wbc  = (const float*)d_in[5];
    const float* bbc  = (const float*)d_in[6];
    const float* Alog = (const float*)d_in[7];
    const float* Dp   = (const float*)d_in[8];
    const float* ln2g = (const float*)d_in[9];
    const float* ln2b = (const float*)d_in[10];
    const float* W1   = (const float*)d_in[11];
    const float* b1   = (const float*)d_in[12];
    const float* W2   = (const float*)d_in[13];
    const float* b2   = (const float*)d_in[14];
    float* out = (float*)d_out;

    char* ws = (char*)d_ws;
    const size_t MB = 1024 * 1024;
    float*  deltaW = (float*)(ws + 0);            // 16 MiB (4096x1024 f32)
    float*  ssmW   = (float*)(ws + 16 * MB);      // 16 MiB (4096x1024 f32)
    USHORT* xnW    = (USHORT*)(ws + 32 * MB);     //  8 MiB (4096x1024 bf16)
    USHORT* nrmW   = (USHORT*)(ws + 40 * MB);     //  8 MiB (4096x1024 bf16)
    USHORT* hffW   = (USHORT*)(ws + 48 * MB);     // 32 MiB (4096x4096 bf16)
    float*  bcW    = (float*)(ws + 80 * MB);      // 512 KiB (4096x32 f32)
    USHORT* WdB    = (USHORT*)(ws + 81 * MB);     //  2 MiB (1024x1024 bf16)
    USHORT* W1B    = (USHORT*)(ws + 83 * MB);     //  8 MiB (4096x1024 bf16)
    USHORT* W2B    = (USHORT*)(ws + 91 * MB);     //  8 MiB (1024x4096 bf16)
    USHORT* WbcB   = (USHORT*)(ws + 99 * MB);     // 64 KiB (32x1024 bf16)
    // delta split-K partials alias hffW (dead until step 6): 2 x 8 MiB
    USHORT* dpart  = (USHORT*)(ws + 48 * MB);
    // scan scratch aliases hffW too (delta reduce finishes first): 3 x 8 MiB
    float*  sEndW  = (float*)(ws + 48 * MB);
    float*  PtotW  = (float*)(ws + 56 * MB);
    float*  sInW   = (float*)(ws + 64 * MB);
    // FFN2 split-K partials alias deltaW (splits 0,1) and xnW/nrmW (splits 2,3)
    USHORT* ffn2p01 = (USHORT*)(ws + 0);          // 16 MiB: 2 x 4096x1024 bf16
    USHORT* ffn2p23 = (USHORT*)(ws + 32 * MB);    // 16 MiB: 2 x 4096x1024 bf16

    // 0. convert weights f32 -> bf16
    f2b_kernel<<<1024, 256, 0, stream>>>(Wd, WdB, 1024 * 1024);
    f2b_kernel<<<4096, 256, 0, stream>>>(W1, W1B, 4096 * 1024);
    f2b_kernel<<<4096, 256, 0, stream>>>(W2, W2B, 1024 * 4096);
    f2b_kernel<<<32, 256, 0, stream>>>(Wbc, WbcB, 32 * 1024);
    // 1. xn = LN1(x)                         (bf16)
    ln_kernel<<<4096, 256, 0, stream>>>(x, ln1g, ln1b, xnW);
    // 2a. delta split-K=2 partial GEMMs      (bf16 partials)
    gemm_bt<3><<<dim3(8, 32, 2), 256, 0, stream>>>(xnW, WdB, nullptr, dpart, nullptr, 4096, 1024, 512, 1024, 1024);
    // 2b. delta = softplus(p0+p1+bd)         (f32)
    delta_reduce<<<4096, 256, 0, stream>>>(dpart, bd, deltaW);
    // 3. bc = xn @ Wbc^T + bbc               (f32), MFMA micro-GEMM
    bc_mfma<<<64, 256, 0, stream>>>(xnW, WbcB, bbc, bcW);
    // 4. ssm_out = x + scan(...) + D*xn      (f32), chunked parallel scan
    scan_pass1<<<dim3(4, 2, SCAN_P), 256, 0, stream>>>(xnW, deltaW, bcW, Alog, sEndW, PtotW);
    scan_mid<<<128, 256, 0, stream>>>(sEndW, PtotW, sInW);
    scan_pass2<<<dim3(4, 2, SCAN_P), 256, 0, stream>>>(x, xnW, deltaW, bcW, Alog, Dp, sInW, ssmW);
    // 5. normed = LN2(ssm_out)               (bf16)
    ln_kernel<<<4096, 256, 0, stream>>>(ssmW, ln2g, ln2b, nrmW);
    // 6. hff = gelu(normed @ W1^T + b1)      (bf16)
    gemm_bt<1><<<dim3(32, 32), 256, 0, stream>>>(nrmW, W1B, b1, hffW, nullptr, 4096, 4096, 1024, 1024, 1024);
    // 7a. FFN2 split-K=4 partial GEMMs       (bf16 partials, grid.z = split)
    gemm_bt<3><<<dim3(8, 32, 4), 256, 0, stream>>>(hffW, W2B, nullptr, ffn2p01, ffn2p23, 4096, 1024, 1024, 4096, 4096);
    // 7b. out = sum(partials) + b2 + ssm_out (f32)
    ffn2_reduce<<<4096, 256, 0, stream>>>(ffn2p01, ffn2p23, b2, ssmW, out);

    (void)in_sizes; (void)n_in; (void)out_size; (void)ws_size;
}